// Round 24
// baseline (303.210 us; speedup 1.0000x reference)
//
#include <hip/hip_runtime.h>
#include <hip/hip_bf16.h>
#include <cmath>
#include <cstdint>

typedef __bf16 bf16_t;
typedef bf16_t bf16x8 __attribute__((ext_vector_type(8)));
typedef bf16_t bf16x4 __attribute__((ext_vector_type(4)));
typedef float f32x4 __attribute__((ext_vector_type(4)));

#define BB 2
#define LL 2048
#define DMODEL 1024
#define DINNER 2048
#define DSTATE 16
#define NC 32      // chunks over L
#define CHUNK 64   // L / NC (processed as two 32-step halves, register-safe)
#define KSEG 256   // split-K segment for the x_dbl GEMM

// fast 2^x via v_exp_f32
#define EXP2F(x) __builtin_amdgcn_exp2f(x)

// ------- fused fp32 -> bf16 convert: x, Win, Wdt, Wo, W_xp(pad), Wos(T) -------
#define CVT_N0 1048576   // x      4096*1024/4
#define CVT_N1 2097152   // + Win  4096*1024/4
#define CVT_N2 2129920   // + Wdt  2048*64/4
#define CVT_N3 2392064   // + Wo   1024*1024/4
#define CVT_NB0 9344     // CVT_N3/256
#define CVT_NB1 10368    // + 1024 wxp blocks
#define CVT_NBT 10880    // + 512 wosT blocks
__global__ __launch_bounds__(256) void k_cvt_all(
    const float* __restrict__ x, const float* __restrict__ Win,
    const float* __restrict__ Wdt, const float* __restrict__ Wo,
    const float* __restrict__ Wxp, const float* __restrict__ Wos,
    bf16_t* __restrict__ x_b, bf16_t* __restrict__ Win_b,
    bf16_t* __restrict__ Wdt_b, bf16_t* __restrict__ Wo_b,
    bf16_t* __restrict__ Wxp_b, bf16_t* __restrict__ WosT_b) {
    const int tid = threadIdx.x;
    if (blockIdx.x < CVT_NB0) {
        int i = blockIdx.x * 256 + tid;
        const float* src; bf16_t* dst; int j;
        if (i < CVT_N0)      { src = x;   dst = x_b;   j = i; }
        else if (i < CVT_N1) { src = Win; dst = Win_b; j = i - CVT_N0; }
        else if (i < CVT_N2) { src = Wdt; dst = Wdt_b; j = i - CVT_N1; }
        else                 { src = Wo;  dst = Wo_b;  j = i - CVT_N2; }
        float4 v = reinterpret_cast<const float4*>(src)[j];
        bf16x4 o;
        o[0] = (bf16_t)v.x; o[1] = (bf16_t)v.y; o[2] = (bf16_t)v.z; o[3] = (bf16_t)v.w;
        reinterpret_cast<bf16x4*>(dst)[j] = o;
    } else if (blockIdx.x < CVT_NB1) {
        int i = (blockIdx.x - CVT_NB0) * 256 + tid;
        int r = i >> 11, c = i & (DINNER - 1);
        float v = (r < 96) ? Wxp[r * DINNER + c] : 0.f;
        Wxp_b[i] = (bf16_t)v;
    } else {
        __shared__ float tile[64][65];
        const int bid = blockIdx.x - CVT_NB1;
        const int m0 = (bid & 15) * 64;
        const int d0 = (bid >> 4) * 64;
        const int dl = tid & 63;
        #pragma unroll 4
        for (int i = 0; i < 16; ++i) {
            const int mr = (tid >> 6) + i * 4;
            tile[dl][mr] = Wos[(size_t)(m0 + mr) * DINNER + d0 + dl];
        }
        __syncthreads();
        const int dr = tid >> 2;
        const int q  = tid & 3;
        bf16_t* op = WosT_b + (size_t)(d0 + dr) * DMODEL + m0 + q * 16;
        bf16x8 v0, v1;
        #pragma unroll
        for (int j = 0; j < 8; ++j) v0[j] = (bf16_t)tile[dr][q * 16 + j];
        #pragma unroll
        for (int j = 0; j < 8; ++j) v1[j] = (bf16_t)tile[dr][q * 16 + 8 + j];
        reinterpret_cast<bf16x8*>(op)[0] = v0;
        reinterpret_cast<bf16x8*>(op)[1] = v1;
    }
}

// ---------------- async global->LDS helper ----------------
__device__ __forceinline__ void gload16(const void* g, void* l) {
    __builtin_amdgcn_global_load_lds(
        (const __attribute__((address_space(1))) void*)g,
        (__attribute__((address_space(3))) void*)l,
        16, 0, 0);
}

// ============ 256x256 BK=64 counted-drain GEMM: xin + zT (256 blocks) ============
// r17/r18-verified structure (0 bank conflicts, correct output, hoisted pointers).
__global__ __launch_bounds__(512) void k_gemm256(
    const bf16_t* __restrict__ x_b, const bf16_t* __restrict__ Win_b,
    bf16_t* __restrict__ xin_b, bf16_t* __restrict__ zsT) {
    __shared__ bf16_t lds[65536];   // 128 KB
    const int tid = threadIdx.x;
    const int wid = tid >> 6, lane = tid & 63;

    const int bid = (blockIdx.x & 7) * 32 + (blockIdx.x >> 3);   // XCD swizzle
    const bf16_t* A; const bf16_t* Bt; int m0, n0, sub;
    if (bid < 128) {  // xin = x @ Win_x^T  [4096, 2048]
        sub = 0; A = x_b; Bt = Win_b;
        m0 = (bid >> 3) * 256; n0 = (bid & 7) * 256;
    } else {          // zT = Win_z @ x^T   [2048, 4096] -> silu
        sub = 1; A = Win_b + (size_t)DINNER * DMODEL; Bt = x_b;
        const int t2 = bid - 128;
        m0 = (t2 >> 4) * 256; n0 = (t2 & 15) * 256;
    }
    const int wr = wid >> 2, wc = wid & 3;   // 2x4 wave grid
    f32x4 acc[8][4] = {};

    const int srow = tid >> 3;
    const int k8p = (tid & 7) ^ (srow & 7);
    const bf16_t* apA = A + (size_t)(m0 + srow) * 1024 + k8p * 8;
    const bf16_t* apB = Bt + (size_t)(n0 + srow) * 1024 + k8p * 8;

    auto stageA = [&](int slot, int kt) {
        char* b0 = (char*)lds + slot * 32768 + wid * 1024;
        const bf16_t* src = apA + kt * 64;
        gload16(src, b0);
        gload16(src + (size_t)64 * 1024, b0 + 8192);
        gload16(src + (size_t)128 * 1024, b0 + 16384);
        gload16(src + (size_t)192 * 1024, b0 + 24576);
    };
    auto stageB = [&](int slot, int kt) {
        char* b0 = (char*)lds + 65536 + slot * 32768 + wid * 1024;
        const bf16_t* src = apB + kt * 64;
        gload16(src, b0);
        gload16(src + (size_t)64 * 1024, b0 + 8192);
        gload16(src + (size_t)128 * 1024, b0 + 16384);
        gload16(src + (size_t)192 * 1024, b0 + 24576);
    };

    const int lm = lane & 15, lq = lane >> 4;

    const bf16_t* pA0[8]; const bf16_t* pA1[8];
    const bf16_t* pB0[4]; const bf16_t* pB1[4];
    #pragma unroll
    for (int i = 0; i < 8; ++i) {
        const int rr = lm + i * 16;
        const int e0 = wr * 8192 + rr * 64 + (lq ^ (rr & 7)) * 8;
        pA0[i] = lds + e0;
        pA1[i] = lds + (e0 ^ 32);
    }
    #pragma unroll
    for (int j = 0; j < 4; ++j) {
        const int rr = (wc & 1) * 64 + lm + j * 16;
        const int e0 = 32768 + (wc >> 1) * 8192 + rr * 64 + (lq ^ (rr & 7)) * 8;
        pB0[j] = lds + e0;
        pB1[j] = lds + (e0 ^ 32);
    }

    auto body = [&](int t, int s) {   // s is a literal at every call site
        asm volatile("s_waitcnt vmcnt(0)" ::: "memory");
        __builtin_amdgcn_sched_barrier(0);
        __builtin_amdgcn_s_barrier();
        __builtin_amdgcn_sched_barrier(0);
        if (t + 1 < 16) {
            stageA(s ^ 1, t + 1);
            stageB(s ^ 1, t + 1);
        }
        {   // ks = 0
            bf16x8 fa[8], fb[4];
            #pragma unroll
            for (int i = 0; i < 8; ++i) fa[i] = *(const bf16x8*)(pA0[i] + s * 16384);
            #pragma unroll
            for (int j = 0; j < 4; ++j) fb[j] = *(const bf16x8*)(pB0[j] + s * 16384);
            __builtin_amdgcn_s_setprio(1);
            #pragma unroll
            for (int i = 0; i < 8; ++i)
                #pragma unroll
                for (int j = 0; j < 4; ++j)
                    acc[i][j] = __builtin_amdgcn_mfma_f32_16x16x32_bf16(fa[i], fb[j], acc[i][j], 0, 0, 0);
            __builtin_amdgcn_s_setprio(0);
        }
        {   // ks = 1
            bf16x8 fa[8], fb[4];
            #pragma unroll
            for (int i = 0; i < 8; ++i) fa[i] = *(const bf16x8*)(pA1[i] + s * 16384);
            #pragma unroll
            for (int j = 0; j < 4; ++j) fb[j] = *(const bf16x8*)(pB1[j] + s * 16384);
            __builtin_amdgcn_s_setprio(1);
            #pragma unroll
            for (int i = 0; i < 8; ++i)
                #pragma unroll
                for (int j = 0; j < 4; ++j)
                    acc[i][j] = __builtin_amdgcn_mfma_f32_16x16x32_bf16(fa[i], fb[j], acc[i][j], 0, 0, 0);
            __builtin_amdgcn_s_setprio(0);
        }
    };

    stageA(0, 0);
    stageB(0, 0);
    for (int tt = 0; tt < 8; ++tt) {
        body(2 * tt, 0);
        body(2 * tt + 1, 1);
    }

    // C/D layout (m89): col = lane&15, row = (lane>>4)*4 + reg
    const int row0 = m0 + wr * 128 + lq * 4;
    const int col0 = n0 + wc * 64 + lm;
    #pragma unroll
    for (int i = 0; i < 8; ++i) {
        #pragma unroll
        for (int j = 0; j < 4; ++j) {
            #pragma unroll
            for (int r = 0; r < 4; ++r) {
                const int row = row0 + i * 16 + r;
                const int c = col0 + j * 16;
                float v = acc[i][j][r];
                if (sub == 0) xin_b[(size_t)row * DINNER + c] = (bf16_t)v;
                else          zsT[(size_t)row * (BB * LL) + c] = (bf16_t)(v / (1.f + __expf(-v)));
            }
        }
    }
}

enum { EPI_BF16 = 0, EPI_BIAS = 1, EPI_SOFTPLUS_RB = 3, EPI_PARTK = 4 };

// ======== 128x128 BK=64 counted-drain GEMM (long-K tail: Wc, out) ========
template <int EPI>
__global__ __launch_bounds__(512) void k_gemm_cd128(
    const bf16_t* __restrict__ A, const bf16_t* __restrict__ Bt,
    int N, int Ktiles, int lda, int ldb,
    float* __restrict__ C, bf16_t* __restrict__ Cb,
    const float* __restrict__ bias) {
    __shared__ bf16_t lds[32768];   // 64 KB
    const int tid = threadIdx.x;
    const int wid = tid >> 6, lane = tid & 63;
    const int bx = (blockIdx.x & 7) * ((int)gridDim.x >> 3) + (blockIdx.x >> 3);  // XCD swizzle
    const int ntile = N >> 7;
    const int m0 = (bx / ntile) << 7;
    const int n0 = (bx % ntile) << 7;
    const int wr = wid >> 2, wc = wid & 3;
    f32x4 acc[4][2] = {};

    const int srow = tid >> 3;
    const int k8p = (tid & 7) ^ (srow & 7);
    const bf16_t* apA = A + (size_t)(m0 + srow) * lda + k8p * 8;
    const bf16_t* apB = Bt + (size_t)(n0 + srow) * ldb + k8p * 8;

    auto stageA = [&](int slot, int kt) {
        char* b0 = (char*)lds + slot * 16384 + wid * 1024;
        const bf16_t* src = apA + kt * 64;
        gload16(src, b0);
        gload16(src + (size_t)64 * lda, b0 + 8192);
    };
    auto stageB = [&](int slot, int kt) {
        char* b0 = (char*)lds + 32768 + slot * 16384 + wid * 1024;
        const bf16_t* src = apB + kt * 64;
        gload16(src, b0);
        gload16(src + (size_t)64 * ldb, b0 + 8192);
    };

    const int lm = lane & 15, lq = lane >> 4;

    const bf16_t* pA0[4]; const bf16_t* pA1[4];
    const bf16_t* pB0[2]; const bf16_t* pB1[2];
    #pragma unroll
    for (int i = 0; i < 4; ++i) {
        const int rr = lm + i * 16;
        const int e0 = wr * 4096 + rr * 64 + (lq ^ (rr & 7)) * 8;
        pA0[i] = lds + e0;
        pA1[i] = lds + (e0 ^ 32);
    }
    #pragma unroll
    for (int j = 0; j < 2; ++j) {
        const int rr = wc * 32 + lm + j * 16;
        const int e0 = 16384 + rr * 64 + (lq ^ (rr & 7)) * 8;
        pB0[j] = lds + e0;
        pB1[j] = lds + (e0 ^ 32);
    }

    auto body = [&](int t, int s) {
        asm volatile("s_waitcnt vmcnt(0)" ::: "memory");
        __builtin_amdgcn_sched_barrier(0);
        __builtin_amdgcn_s_barrier();
        __builtin_amdgcn_sched_barrier(0);
        if (t + 1 < Ktiles) {
            stageA(s ^ 1, t + 1);
            stageB(s ^ 1, t + 1);
        }
        {   // ks = 0
            bf16x8 fa[4], fb[2];
            #pragma unroll
            for (int i = 0; i < 4; ++i) fa[i] = *(const bf16x8*)(pA0[i] + s * 8192);
            #pragma unroll
            for (int j = 0; j < 2; ++j) fb[j] = *(const bf16x8*)(pB0[j] + s * 8192);
            __builtin_amdgcn_s_setprio(1);
            #pragma unroll
            for (int i = 0; i < 4; ++i)
                #pragma unroll
                for (int j = 0; j < 2; ++j)
                    acc[i][j] = __builtin_amdgcn_mfma_f32_16x16x32_bf16(fa[i], fb[j], acc[i][j], 0, 0, 0);
            __builtin_amdgcn_s_setprio(0);
        }
        {   // ks = 1
            bf16x8 fa[4], fb[2];
            #pragma unroll
            for (int i = 0; i < 4; ++i) fa[i] = *(const bf16x8*)(pA1[i] + s * 8192);
            #pragma unroll
            for (int j = 0; j < 2; ++j) fb[j] = *(const bf16x8*)(pB1[j] + s * 8192);
            __builtin_amdgcn_s_setprio(1);
            #pragma unroll
            for (int i = 0; i < 4; ++i)
                #pragma unroll
                for (int j = 0; j < 2; ++j)
                    acc[i][j] = __builtin_amdgcn_mfma_f32_16x16x32_bf16(fa[i], fb[j], acc[i][j], 0, 0, 0);
            __builtin_amdgcn_s_setprio(0);
        }
    };

    stageA(0, 0);
    stageB(0, 0);
    for (int tt = 0; tt < (Ktiles >> 1); ++tt) {
        body(2 * tt, 0);
        body(2 * tt + 1, 1);
    }

    // C/D layout (m89): col = lane&15, row = (lane>>4)*4 + reg
    const int row0 = m0 + wr * 64 + lq * 4;
    const int col0 = n0 + wc * 32 + lm;
    #pragma unroll
    for (int i = 0; i < 4; ++i) {
        #pragma unroll
        for (int j = 0; j < 2; ++j) {
            #pragma unroll
            for (int r = 0; r < 4; ++r) {
                const int row = row0 + i * 16 + r;
                const int c = col0 + j * 16;
                float v = acc[i][j][r];
                if (EPI == EPI_BF16) Cb[(size_t)row * N + c] = (bf16_t)v;
                else                 C[(size_t)row * N + c] = v + bias[c];
            }
        }
    }
}

// ---------------- 2-phase 128x128 GEMM (short-K: partk, dt) ----------------
template <int EPI>
__global__ __launch_bounds__(512) void k_gemm_bt(
    const bf16_t* __restrict__ A, const bf16_t* __restrict__ Bt,
    int M, int N, int Kloop, int lda, int ldb,
    float* __restrict__ C, bf16_t* __restrict__ Cb,
    const float* __restrict__ bias,
    float* __restrict__ o_part) {
    __shared__ bf16_t sA[2][128 * 32];
    __shared__ bf16_t sB[2][128 * 32];
    const int tid = threadIdx.x;
    const int wid = tid >> 6, lane = tid & 63;
    const int bx = (blockIdx.x & 7) * ((int)gridDim.x >> 3) + (blockIdx.x >> 3);  // XCD swizzle
    int m0, n0, k0 = 0, seg = 0;
    if (EPI == EPI_PARTK) {
        m0 = (bx & 31) << 7;
        n0 = 0;
        seg = bx >> 5;
        k0 = seg * KSEG;
    } else {
        const int ntile = N >> 7;
        m0 = (bx / ntile) << 7;
        n0 = (bx % ntile) << 7;
    }
    const int wr = wid >> 2, wc = wid & 3;   // 2x4 wave grid; wave tile 64x32
    f32x4 acc[4][2] = {};

    const bf16_t* ap = A + (size_t)(m0 + (tid >> 2)) * lda + (tid & 3) * 8 + k0;
    const bf16_t* bp = Bt + (size_t)(n0 + (tid >> 2)) * ldb + (tid & 3) * 8 + k0;
    const int lm = lane & 15, lk = (lane >> 4) * 8;

    auto stage = [&](int buf, int kt) {
        char* dA = (char*)sA[buf] + wid * 1024;
        char* dB = (char*)sB[buf] + wid * 1024;
        gload16(ap + kt, dA);
        gload16(bp + kt, dB);
    };

    stage(0, 0);
    __syncthreads();
    int cur = 0;
    for (int kt = 0; kt < Kloop; kt += 32) {
        if (kt + 32 < Kloop) stage(cur ^ 1, kt + 32);
        const bf16_t* rA = sA[cur] + (wr * 64 + lm) * 32 + lk;
        const bf16_t* rB = sB[cur] + (wc * 32 + lm) * 32 + lk;
        bf16x8 fa[4], fb[2];
        #pragma unroll
        for (int i = 0; i < 4; ++i) fa[i] = *(const bf16x8*)(rA + i * 16 * 32);
        #pragma unroll
        for (int j = 0; j < 2; ++j) fb[j] = *(const bf16x8*)(rB + j * 16 * 32);
        __builtin_amdgcn_s_setprio(1);
        #pragma unroll
        for (int i = 0; i < 4; ++i)
            #pragma unroll
            for (int j = 0; j < 2; ++j)
                acc[i][j] = __builtin_amdgcn_mfma_f32_16x16x32_bf16(fa[i], fb[j], acc[i][j], 0, 0, 0);
        __builtin_amdgcn_s_setprio(0);
        __syncthreads();
        cur ^= 1;
    }

    // C/D layout (m89-verified): col = lane&15, row = (lane>>4)*4 + reg
    const int row0 = m0 + wr * 64 + (lane >> 4) * 4;
    const int col0 = n0 + wc * 32 + lm;
    float* Cp = (EPI == EPI_PARTK)
        ? o_part + (size_t)seg * ((size_t)4096 * 128)
        : C;
    #pragma unroll
    for (int i = 0; i < 4; ++i) {
        #pragma unroll
        for (int j = 0; j < 2; ++j) {
            #pragma unroll
            for (int r = 0; r < 4; ++r) {
                int row = row0 + i * 16 + r;
                int c = col0 + j * 16;
                float v = acc[i][j][r];
                if (EPI == EPI_SOFTPLUS_RB) {
                    float xv = v + bias[row];
                    float sp = fmaxf(xv, 0.f) + log1pf(__expf(-fabsf(xv)));
                    Cb[(size_t)row * N + c] = (bf16_t)sp;
                } else {  // EPI_PARTK
                    Cp[(size_t)row * 128 + c] = v;
                }
            }
        }
    }
}

// ---------------- split-K reduce + x_dbl split: dtr bf16 / B f32 / C f32 ----
__global__ __launch_bounds__(256) void k_split_reduce(
    const float* __restrict__ part, bf16_t* __restrict__ dtr,
    float* __restrict__ Bmf, float* __restrict__ Cmf) {
    int idx = blockIdx.x * 256 + threadIdx.x;   // over 4096*128
    int row = idx >> 7, c = idx & 127;
    float s = 0.f;
    #pragma unroll
    for (int g = 0; g < 8; ++g) s += part[(size_t)g * (4096 * 128) + idx];
    if (c < 64) dtr[(size_t)row * 64 + c] = (bf16_t)s;
    else if (c < 80) Bmf[(size_t)row * 16 + (c - 64)] = s;
    else if (c < 96) Cmf[(size_t)row * 16 + (c - 80)] = s;
}

// ---------------- causal depthwise conv (k=4) + bias + SiLU ----------------
__global__ __launch_bounds__(256) void k_conv(
    const bf16_t* __restrict__ xin, const float* __restrict__ cw,
    const float* __restrict__ cb, bf16_t* __restrict__ xs_b,
    bf16_t* __restrict__ xsT) {
    __shared__ float tile[64][65];
    const int tid = threadIdx.x;
    const int d0  = (blockIdx.x & 31) * 64;
    const int bl0 = (blockIdx.x >> 5) * 64;
    const int dl = tid & 63;
    const int d  = d0 + dl;
    const float w0 = cw[d * 4], w1 = cw[d * 4 + 1], w2 = cw[d * 4 + 2], w3 = cw[d * 4 + 3];
    const float bias = cb[d];
    const int l0 = bl0 & (LL - 1);   // tiles never cross a batch boundary
    #pragma unroll 4
    for (int i = 0; i < 16; ++i) {
        const int blr = (tid >> 6) + i * 4;
        const int bl = bl0 + blr;
        const int l  = l0 + blr;
        const bf16_t* rp = xin + (size_t)bl * DINNER + d;
        float acc = fmaf(w3, (float)rp[0], bias);
        if (l >= 1) acc = fmaf(w2, (float)rp[-(int)DINNER], acc);
        if (l >= 2) acc = fmaf(w1, (float)rp[-2 * (int)DINNER], acc);
        if (l >= 3) acc = fmaf(w0, (float)rp[-3 * (int)DINNER], acc);
        float sv = acc / (1.f + __expf(-acc));
        xs_b[(size_t)bl * DINNER + d] = (bf16_t)sv;
        tile[dl][blr] = sv;
    }
    __syncthreads();
    const int dr = tid >> 2;
    const int q  = tid & 3;
    bf16_t* op = xsT + (size_t)(d0 + dr) * (BB * LL) + bl0 + q * 16;
    bf16x8 v0, v1;
    #pragma unroll
    for (int j = 0; j < 8; ++j) v0[j] = (bf16_t)tile[dr][q * 16 + j];
    #pragma unroll
    for (int j = 0; j < 8; ++j) v1[j] = (bf16_t)tile[dr][q * 16 + 8 + j];
    reinterpret_cast<bf16x8*>(op)[0] = v0;
    reinterpret_cast<bf16x8*>(op)[1] = v1;
}

// ================= chunked selective scan, lane-owns-channel =================
// CHUNK=64 processed as two 32-step halves (register footprint unchanged).
// alpha/beta/H stored as bf16.

__global__ __launch_bounds__(256) void k_scan_p1(
    const bf16_t* __restrict__ dtT, const bf16_t* __restrict__ xsT,
    const float* __restrict__ Bm, const float* __restrict__ A_log,
    bf16_t* __restrict__ alpha, bf16_t* __restrict__ beta) {
    __shared__ float sB[CHUNK * 16];   // 4 KB
    const int db = blockIdx.x & 7;
    const int ck = (blockIdx.x >> 3) & (NC - 1);
    const int b  = blockIdx.x >> 8;
    const int tid = threadIdx.x;
    const int d  = db * 256 + tid;
    const int t0 = ck * CHUNK;

    const float* Bsrc = Bm + ((size_t)b * LL + t0) * 16;
    sB[tid] = Bsrc[tid];
    sB[tid + 256] = Bsrc[tid + 256];
    sB[tid + 512] = Bsrc[tid + 512];
    sB[tid + 768] = Bsrc[tid + 768];

    f32x4 a2[4];
    #pragma unroll
    for (int q = 0; q < 4; ++q) {
        f32x4 av = reinterpret_cast<const f32x4*>(A_log + d * 16)[q];
        #pragma unroll
        for (int j = 0; j < 4; ++j) a2[q][j] = -__expf(av[j]) * 1.44269504f;
    }
    const bf16x8* dtp = reinterpret_cast<const bf16x8*>(dtT + (size_t)d * (BB * LL) + b * LL + t0);
    const bf16x8* xsp = reinterpret_cast<const bf16x8*>(xsT + (size_t)d * (BB * LL) + b * LL + t0);

    __syncthreads();

    // alpha = exp2(a2[s] * sum_t dtv); beta keeps the per-step recurrence.
    float be[16];
    #pragma unroll
    for (int s = 0; s < 16; ++s) be[s] = 0.f;
    float dtsum = 0.f;

    for (int hf = 0; hf < 2; ++hf) {
        bf16x8 dtl[4], xsl[4];
        #pragma unroll
        for (int q = 0; q < 4; ++q) dtl[q] = dtp[hf * 4 + q];
        #pragma unroll
        for (int q = 0; q < 4; ++q) xsl[q] = xsp[hf * 4 + q];
        const float* sBh = sB + hf * 32 * 16;
        #pragma unroll
        for (int t = 0; t < 32; ++t) {
            float dtv = (float)dtl[t >> 3][t & 7];
            float xv  = (float)xsl[t >> 3][t & 7];
            float dtx = dtv * xv;
            dtsum += dtv;
            #pragma unroll
            for (int q = 0; q < 4; ++q) {
                f32x4 Bq = *reinterpret_cast<const f32x4*>(sBh + t * 16 + q * 4);
                #pragma unroll
                for (int j = 0; j < 4; ++j) {
                    const int s = q * 4 + j;
                    float dA = EXP2F(dtv * a2[q][j]);
                    be[s] = fmaf(be[s], dA, dtx * Bq[j]);
                }
            }
        }
    }
    bf16_t* ap = alpha + ((size_t)(b * NC + ck)) * (DINNER * 16) + (size_t)d * 16;
    bf16_t* bp = beta  + ((size_t)(b * NC + ck)) * (DINNER * 16) + (size_t)d * 16;
    bf16x8 av0, av1, bv0, bv1;
    #pragma unroll
    for (int j = 0; j < 8; ++j) {
        av0[j] = (bf16_t)EXP2F(a2[j >> 2][j & 3] * dtsum);
        av1[j] = (bf16_t)EXP2F(a2[(j + 8) >> 2][j & 3] * dtsum);
        bv0[j] = (bf16_t)be[j];
        bv1[j] = (bf16_t)be[8 + j];
    }
    reinterpret_cast<bf16x8*>(ap)[0] = av0;
    reinterpret_cast<bf16x8*>(ap)[1] = av1;
    reinterpret_cast<bf16x8*>(bp)[0] = bv0;
    reinterpret_cast<bf16x8*>(bp)[1] = bv1;
}

__global__ __launch_bounds__(256) void k_scan_p2(
    const bf16_t* __restrict__ alpha, const bf16_t* __restrict__ beta,
    bf16_t* __restrict__ H) {
    const int gid = blockIdx.x * 256 + threadIdx.x;   // over B*DINNER*16
    const int b = gid >> 15, r = gid & 32767;
    float h = 0.f;
    #pragma unroll 8
    for (int ck = 0; ck < NC; ++ck) {
        const size_t i = ((size_t)(b * NC + ck)) * 32768 + r;
        H[i] = (bf16_t)h;
        h = fmaf((float)alpha[i], h, (float)beta[i]);
    }
}

__global__ __launch_bounds__(256) void k_scan_p3(
    const bf16_t* __restrict__ dtT, const bf16_t* __restrict__ xsT,
    const float* __restrict__ Bm, const float* __restrict__ Cm,
    const bf16_t* __restrict__ zsT, const float* __restrict__ A_log,
    const float* __restrict__ Dp, const bf16_t* __restrict__ H,
    bf16_t* __restrict__ y) {
    __shared__ float sB[CHUNK * 16];   // 4 KB
    __shared__ float sC[CHUNK * 16];   // 4 KB
    const int db = blockIdx.x & 7;
    const int ck = (blockIdx.x >> 3) & (NC - 1);
    const int b  = blockIdx.x >> 8;
    const int tid = threadIdx.x;
    const int d  = db * 256 + tid;
    const int t0 = ck * CHUNK;

    const float* Bsrc = Bm + ((size_t)b * LL + t0) * 16;
    const float* Csrc = Cm + ((size_t)b * LL + t0) * 16;
    sB[tid] = Bsrc[tid];
    sB[tid + 256] = Bsrc[tid + 256];
    sB[tid + 512] = Bsrc[tid + 512];
    sB[tid + 768] = Bsrc[tid + 768];
    sC[tid] = Csrc[tid];
    sC[tid + 256] = Csrc[tid + 256];
    sC[tid + 512] = Csrc[tid + 512];
    sC[tid + 768] = Csrc[tid + 768];

    f32x4 a2[4];
    #pragma unroll
    for (int q = 0; q < 4; ++q) {
        f32x4 av = reinterpret_cast<const f32x4*>(A_log + d * 16)[q];
        #pragma unroll
        for (int j = 0; j < 4; ++j) a2[q][j] = -__expf(av[j]) * 1.44269504f;
    }
    const float Dd = Dp[d];
    const bf16x8* dtp = reinterpret_cast<const bf16x8*>(dtT + (size_t)d * (BB * LL) + b * LL + t0);
    const bf16x8* xsp = reinterpret_cast<const bf16x8*>(xsT + (size_t)d * (BB * LL) + b * LL + t0);
    const bf16x8* zp  = reinterpret_cast<const bf16x8*>(zsT + (size_t)d * (BB * LL) + b * LL + t0);
    bf16_t* yp = y + ((size_t)b * LL + t0) * DINNER + d;

    float h[16];
    {
        const bf16x8* hp = reinterpret_cast<const bf16x8*>(H + ((size_t)(b * NC + ck)) * 32768 + (size_t)d * 16);
        bf16x8 h0 = hp[0], h1 = hp[1];
        #pragma unroll
        for (int j = 0; j < 8; ++j) { h[j] = (float)h0[j]; h[8 + j] = (float)h1[j]; }
    }

    __syncthreads();

    for (int hf = 0; hf < 2; ++hf) {
        bf16x8 dtl[4], xsl[4], zsl[4];
        #pragma unroll
        for (int q = 0; q < 4; ++q) dtl[q] = dtp[hf * 4 + q];
        #pragma unroll
        for (int q = 0; q < 4; ++q) xsl[q] = xsp[hf * 4 + q];
        #pragma unroll
        for (int q = 0; q < 4; ++q) zsl[q] = zp[hf * 4 + q];
        const float* sBh = sB + hf * 32 * 16;
        const float* sCh = sC + hf * 32 * 16;
        bf16_t* yph = yp + (size_t)(hf * 32) * DINNER;
        #pragma unroll
        for (int t = 0; t < 32; ++t) {
            float dtv = (float)dtl[t >> 3][t & 7];
            float xv  = (float)xsl[t >> 3][t & 7];
            float zv  = (float)zsl[t >> 3][t & 7];
            float dtx = dtv * xv;
            float yacc = 0.f;
            #pragma unroll
            for (int q = 0; q < 4; ++q) {
                f32x4 Bq = *reinterpret_cast<const f32x4*>(sBh + t * 16 + q * 4);
                f32x4 Cq = *reinterpret_cast<const f32x4*>(sCh + t * 16 + q * 4);
                #pragma unroll
                for (int j = 0; j < 4; ++j) {
                    const int s = q * 4 + j;
                    float dA = EXP2F(dtv * a2[q][j]);
                    h[s] = fmaf(h[s], dA, dtx * Bq[j]);
                    yacc = fmaf(h[s], Cq[j], yacc);
                }
            }
            float yv = (yacc + xv * Dd) * zv;   // z already silu'd
            yph[(size_t)t * DINNER] = (bf16_t)yv;
        }
    }
}

extern "C" void kernel_launch(void* const* d_in, const int* in_sizes, int n_in,
                              void* d_out, int out_size, void* d_ws, size_t ws_size,
                              hipStream_t stream) {
    const float* x      = (const float*)d_in[0];
    const float* W_in   = (const float*)d_in[1];
    const float* conv_w = (const float*)d_in[2];
    const float* conv_b = (const float*)d_in[3];
    const float* W_xp   = (const float*)d_in[4];
    const float* W_dt   = (const float*)d_in[5];
    const float* b_dt   = (const float*)d_in[6];
    const float* A_log  = (const float*)d_in[7];
    const float* Dvec   = (const float*)d_in[8];
    const float* W_os   = (const float*)d_in[9];
    const float* W_o    = (const float*)d_in[10];
    const float* b_o    = (const float*)d_in[11];
    float* out = (float*)d_out;

    char* base = (char*)d_ws;
    size_t off = 0;
    auto alloc = [&](size_t bytes) -> char* {
        char* p = base + off;
        off += (bytes + 255) & ~(size_t)255;
        return p;
    };
    const int MR = BB * LL;  // 4096 rows
    bf16_t* x_b   = (bf16_t*)alloc((size_t)MR * DMODEL * 2);     // 8 MiB
    bf16_t* Win_b = (bf16_t*)alloc((size_t)4096 * 1024 * 2);     // 8 MiB
    bf16_t* xin_b = (bf16_t*)alloc((size_t)MR * DINNER * 2);     // 16 MiB (aliased by alpha)
    bf16_t* xs_b  = (bf16_t*)alloc((size_t)MR * DINNER * 2);     // 16 MiB
    bf16_t* zsT   = (bf16_t*)alloc((size_t)DINNER * MR * 2);     // 16 MiB
    bf16_t* xsT   = (bf16_t*)alloc((size_t)DINNER * MR * 2);     // 16 MiB
    bf16_t* dtT_b = (bf16_t*)alloc((size_t)DINNER * MR * 2);     // 16 MiB
    float*  Hbuf  = (float*)alloc((size_t)4096 * 128 * 8 * 4);   // 16 MiB (partk; H bf16 uses 4 MiB)
    bf16_t* y_b   = (bf16_t*)alloc((size_t)MR * DINNER * 2);     // 16 MiB
    bf16_t* dtr_b = (bf16_t*)alloc((size_t)MR * 64 * 2);
    float*  Bmf   = (float*)alloc((size_t)MR * 16 * 4);
    float*  Cmf   = (float*)alloc((size_t)MR * 16 * 4);
    bf16_t* Wxp_b = (bf16_t*)alloc((size_t)128 * DINNER * 2);
    bf16_t* Wdt_b = (bf16_t*)alloc((size_t)DINNER * 64 * 2);
    bf16_t* WosT_b= (bf16_t*)alloc((size_t)DINNER * DMODEL * 2); // 4 MiB
    bf16_t* Wo_b  = (bf16_t*)alloc((size_t)DMODEL * DMODEL * 2); // 2 MiB
    bf16_t* Wc_b  = (bf16_t*)alloc((size_t)DMODEL * DINNER * 2); // 4 MiB

    // aliases (lifetimes disjoint):
    //   alpha (4 MiB bf16) -> xin_b (dead after k_conv)
    //   beta  (4 MiB bf16) -> x_b (dead after k_gemm256)
    //   partk (16 MiB f32) -> Hbuf; H (4 MiB bf16) -> Hbuf (partials dead after reduce)
    bf16_t* alphab = (bf16_t*)xin_b;
    bf16_t* betab  = (bf16_t*)x_b;
    float*  partk  = Hbuf;
    bf16_t* Hb     = (bf16_t*)Hbuf;

    // all bf16 conversions (x, Win, Wdt, Wo, Wxp-pad, Wos-transpose) in one launch
    k_cvt_all<<<CVT_NBT, 256, 0, stream>>>(
        x, W_in, W_dt, W_o, W_xp, W_os,
        x_b, Win_b, Wdt_b, Wo_b, Wxp_b, WosT_b);

    // Wc = Wo @ Wos^T  [1024,2048] K=1024 -> bf16 (fused output projection)
    k_gemm_cd128<EPI_BF16><<<(DMODEL / 128) * (DINNER / 128), 512, 0, stream>>>(
        Wo_b, WosT_b, DINNER, 16, DMODEL, DMODEL, nullptr, Wc_b, nullptr);
    // xin = x @ Win_x^T [4096,2048] | zT = silu(Win_z @ x^T) [2048,4096] [d][t]
    k_gemm256<<<256, 512, 0, stream>>>(x_b, Win_b, xin_b, zsT);
    // conv + silu -> xs_b [t][d] bf16, xsT [d][t] bf16
    k_conv<<<(MR / 64) * (DINNER / 64), 256, 0, stream>>>(xin_b, conv_w, conv_b, xs_b, xsT);
    // x_dbl = xs @ W_xp^T, split-K x8 -> fp32 partials (aliased to Hbuf)
    k_gemm_bt<EPI_PARTK><<<8 * 32, 512, 0, stream>>>(
        xs_b, Wxp_b, MR, 128, KSEG, DINNER, DINNER,
        nullptr, nullptr, nullptr, partk);
    k_split_reduce<<<(MR * 128) / 256, 256, 0, stream>>>(partk, dtr_b, Bmf, Cmf);
    // dtT = softplus(Wdt @ dtr^T + b_dt[row])  [2048,4096] K=64 -> bf16 [d][t]
    k_gemm_bt<EPI_SOFTPLUS_RB><<<(DINNER / 128) * (MR / 128), 512, 0, stream>>>(
        Wdt_b, dtr_b, DINNER, MR, 64, 64, 64,
        nullptr, dtT_b, b_dt, nullptr);
    // chunked selective scan + gate -> y (bf16)
    k_scan_p1<<<BB * NC * (DINNER / 256), 256, 0, stream>>>(dtT_b, xsT, Bmf, A_log, alphab, betab);
    k_scan_p2<<<(BB * DINNER * DSTATE) / 256, 256, 0, stream>>>(alphab, betab, Hb);
    k_scan_p3<<<BB * NC * (DINNER / 256), 256, 0, stream>>>(dtT_b, xsT, Bmf, Cmf, zsT, A_log, Dvec, Hb, y_b);
    // out = y @ Wc^T + b_out  [4096,1024] K=2048 -> fp32
    k_gemm_cd128<EPI_BIAS><<<(MR / 128) * (DMODEL / 128), 512, 0, stream>>>(
        y_b, Wc_b, DMODEL, 32, DINNER, DINNER, out, nullptr, b_o);
}

// Round 25
// 211.868 us; speedup vs baseline: 1.4311x; 1.4311x over previous
//
#include <hip/hip_runtime.h>
#include <hip/hip_bf16.h>
#include <cmath>
#include <cstdint>

typedef __bf16 bf16_t;
typedef bf16_t bf16x8 __attribute__((ext_vector_type(8)));
typedef bf16_t bf16x4 __attribute__((ext_vector_type(4)));
typedef float f32x4 __attribute__((ext_vector_type(4)));

#define BB 2
#define LL 2048
#define DMODEL 1024
#define DINNER 2048
#define DSTATE 16
#define NC 64      // chunks over L
#define CHUNK 32   // L / NC
#define KSEG 256   // split-K segment for the x_dbl GEMM

// fast 2^x via v_exp_f32
#define EXP2F(x) __builtin_amdgcn_exp2f(x)

// ------- fused fp32 -> bf16 convert: x, Win, Wdt, Wo, W_xp(pad), Wos(T) -------
#define CVT_N0 1048576   // x      4096*1024/4
#define CVT_N1 2097152   // + Win  4096*1024/4
#define CVT_N2 2129920   // + Wdt  2048*64/4
#define CVT_N3 2392064   // + Wo   1024*1024/4
#define CVT_NB0 9344     // CVT_N3/256
#define CVT_NB1 10368    // + 1024 wxp blocks
#define CVT_NBT 10880    // + 512 wosT blocks
__global__ __launch_bounds__(256) void k_cvt_all(
    const float* __restrict__ x, const float* __restrict__ Win,
    const float* __restrict__ Wdt, const float* __restrict__ Wo,
    const float* __restrict__ Wxp, const float* __restrict__ Wos,
    bf16_t* __restrict__ x_b, bf16_t* __restrict__ Win_b,
    bf16_t* __restrict__ Wdt_b, bf16_t* __restrict__ Wo_b,
    bf16_t* __restrict__ Wxp_b, bf16_t* __restrict__ WosT_b) {
    const int tid = threadIdx.x;
    if (blockIdx.x < CVT_NB0) {
        int i = blockIdx.x * 256 + tid;
        const float* src; bf16_t* dst; int j;
        if (i < CVT_N0)      { src = x;   dst = x_b;   j = i; }
        else if (i < CVT_N1) { src = Win; dst = Win_b; j = i - CVT_N0; }
        else if (i < CVT_N2) { src = Wdt; dst = Wdt_b; j = i - CVT_N1; }
        else                 { src = Wo;  dst = Wo_b;  j = i - CVT_N2; }
        float4 v = reinterpret_cast<const float4*>(src)[j];
        bf16x4 o;
        o[0] = (bf16_t)v.x; o[1] = (bf16_t)v.y; o[2] = (bf16_t)v.z; o[3] = (bf16_t)v.w;
        reinterpret_cast<bf16x4*>(dst)[j] = o;
    } else if (blockIdx.x < CVT_NB1) {
        int i = (blockIdx.x - CVT_NB0) * 256 + tid;
        int r = i >> 11, c = i & (DINNER - 1);
        float v = (r < 96) ? Wxp[r * DINNER + c] : 0.f;
        Wxp_b[i] = (bf16_t)v;
    } else {
        __shared__ float tile[64][65];
        const int bid = blockIdx.x - CVT_NB1;
        const int m0 = (bid & 15) * 64;
        const int d0 = (bid >> 4) * 64;
        const int dl = tid & 63;
        #pragma unroll 4
        for (int i = 0; i < 16; ++i) {
            const int mr = (tid >> 6) + i * 4;
            tile[dl][mr] = Wos[(size_t)(m0 + mr) * DINNER + d0 + dl];
        }
        __syncthreads();
        const int dr = tid >> 2;
        const int q  = tid & 3;
        bf16_t* op = WosT_b + (size_t)(d0 + dr) * DMODEL + m0 + q * 16;
        bf16x8 v0, v1;
        #pragma unroll
        for (int j = 0; j < 8; ++j) v0[j] = (bf16_t)tile[dr][q * 16 + j];
        #pragma unroll
        for (int j = 0; j < 8; ++j) v1[j] = (bf16_t)tile[dr][q * 16 + 8 + j];
        reinterpret_cast<bf16x8*>(op)[0] = v0;
        reinterpret_cast<bf16x8*>(op)[1] = v1;
    }
}

// ---------------- async global->LDS helper ----------------
__device__ __forceinline__ void gload16(const void* g, void* l) {
    __builtin_amdgcn_global_load_lds(
        (const __attribute__((address_space(1))) void*)g,
        (__attribute__((address_space(3))) void*)l,
        16, 0, 0);
}

// ============ 256x256 BK=64 counted-drain GEMM: xin + zT (256 blocks) ============
// r17/r18-verified structure (0 bank conflicts, correct output, hoisted pointers).
__global__ __launch_bounds__(512) void k_gemm256(
    const bf16_t* __restrict__ x_b, const bf16_t* __restrict__ Win_b,
    bf16_t* __restrict__ xin_b, bf16_t* __restrict__ zsT) {
    __shared__ bf16_t lds[65536];   // 128 KB
    const int tid = threadIdx.x;
    const int wid = tid >> 6, lane = tid & 63;

    const int bid = (blockIdx.x & 7) * 32 + (blockIdx.x >> 3);   // XCD swizzle
    const bf16_t* A; const bf16_t* Bt; int m0, n0, sub;
    if (bid < 128) {  // xin = x @ Win_x^T  [4096, 2048]
        sub = 0; A = x_b; Bt = Win_b;
        m0 = (bid >> 3) * 256; n0 = (bid & 7) * 256;
    } else {          // zT = Win_z @ x^T   [2048, 4096] -> silu
        sub = 1; A = Win_b + (size_t)DINNER * DMODEL; Bt = x_b;
        const int t2 = bid - 128;
        m0 = (t2 >> 4) * 256; n0 = (t2 & 15) * 256;
    }
    const int wr = wid >> 2, wc = wid & 3;   // 2x4 wave grid
    f32x4 acc[8][4] = {};

    const int srow = tid >> 3;
    const int k8p = (tid & 7) ^ (srow & 7);
    const bf16_t* apA = A + (size_t)(m0 + srow) * 1024 + k8p * 8;
    const bf16_t* apB = Bt + (size_t)(n0 + srow) * 1024 + k8p * 8;

    auto stageA = [&](int slot, int kt) {
        char* b0 = (char*)lds + slot * 32768 + wid * 1024;
        const bf16_t* src = apA + kt * 64;
        gload16(src, b0);
        gload16(src + (size_t)64 * 1024, b0 + 8192);
        gload16(src + (size_t)128 * 1024, b0 + 16384);
        gload16(src + (size_t)192 * 1024, b0 + 24576);
    };
    auto stageB = [&](int slot, int kt) {
        char* b0 = (char*)lds + 65536 + slot * 32768 + wid * 1024;
        const bf16_t* src = apB + kt * 64;
        gload16(src, b0);
        gload16(src + (size_t)64 * 1024, b0 + 8192);
        gload16(src + (size_t)128 * 1024, b0 + 16384);
        gload16(src + (size_t)192 * 1024, b0 + 24576);
    };

    const int lm = lane & 15, lq = lane >> 4;

    const bf16_t* pA0[8]; const bf16_t* pA1[8];
    const bf16_t* pB0[4]; const bf16_t* pB1[4];
    #pragma unroll
    for (int i = 0; i < 8; ++i) {
        const int rr = lm + i * 16;
        const int e0 = wr * 8192 + rr * 64 + (lq ^ (rr & 7)) * 8;
        pA0[i] = lds + e0;
        pA1[i] = lds + (e0 ^ 32);
    }
    #pragma unroll
    for (int j = 0; j < 4; ++j) {
        const int rr = (wc & 1) * 64 + lm + j * 16;
        const int e0 = 32768 + (wc >> 1) * 8192 + rr * 64 + (lq ^ (rr & 7)) * 8;
        pB0[j] = lds + e0;
        pB1[j] = lds + (e0 ^ 32);
    }

    auto body = [&](int t, int s) {   // s is a literal at every call site
        asm volatile("s_waitcnt vmcnt(0)" ::: "memory");
        __builtin_amdgcn_sched_barrier(0);
        __builtin_amdgcn_s_barrier();
        __builtin_amdgcn_sched_barrier(0);
        if (t + 1 < 16) {
            stageA(s ^ 1, t + 1);
            stageB(s ^ 1, t + 1);
        }
        {   // ks = 0
            bf16x8 fa[8], fb[4];
            #pragma unroll
            for (int i = 0; i < 8; ++i) fa[i] = *(const bf16x8*)(pA0[i] + s * 16384);
            #pragma unroll
            for (int j = 0; j < 4; ++j) fb[j] = *(const bf16x8*)(pB0[j] + s * 16384);
            __builtin_amdgcn_s_setprio(1);
            #pragma unroll
            for (int i = 0; i < 8; ++i)
                #pragma unroll
                for (int j = 0; j < 4; ++j)
                    acc[i][j] = __builtin_amdgcn_mfma_f32_16x16x32_bf16(fa[i], fb[j], acc[i][j], 0, 0, 0);
            __builtin_amdgcn_s_setprio(0);
        }
        {   // ks = 1
            bf16x8 fa[8], fb[4];
            #pragma unroll
            for (int i = 0; i < 8; ++i) fa[i] = *(const bf16x8*)(pA1[i] + s * 16384);
            #pragma unroll
            for (int j = 0; j < 4; ++j) fb[j] = *(const bf16x8*)(pB1[j] + s * 16384);
            __builtin_amdgcn_s_setprio(1);
            #pragma unroll
            for (int i = 0; i < 8; ++i)
                #pragma unroll
                for (int j = 0; j < 4; ++j)
                    acc[i][j] = __builtin_amdgcn_mfma_f32_16x16x32_bf16(fa[i], fb[j], acc[i][j], 0, 0, 0);
            __builtin_amdgcn_s_setprio(0);
        }
    };

    stageA(0, 0);
    stageB(0, 0);
    for (int tt = 0; tt < 8; ++tt) {
        body(2 * tt, 0);
        body(2 * tt + 1, 1);
    }

    // C/D layout (m89): col = lane&15, row = (lane>>4)*4 + reg
    const int row0 = m0 + wr * 128 + lq * 4;
    const int col0 = n0 + wc * 64 + lm;
    #pragma unroll
    for (int i = 0; i < 8; ++i) {
        #pragma unroll
        for (int j = 0; j < 4; ++j) {
            #pragma unroll
            for (int r = 0; r < 4; ++r) {
                const int row = row0 + i * 16 + r;
                const int c = col0 + j * 16;
                float v = acc[i][j][r];
                if (sub == 0) xin_b[(size_t)row * DINNER + c] = (bf16_t)v;
                else          zsT[(size_t)row * (BB * LL) + c] = (bf16_t)(v / (1.f + __expf(-v)));
            }
        }
    }
}

enum { EPI_BF16 = 0, EPI_BIAS = 1, EPI_SOFTPLUS_RB = 3, EPI_PARTK = 4 };

// ======== 128x128 BK=64 counted-drain GEMM (long-K tail: Wc, out) ========
template <int EPI>
__global__ __launch_bounds__(512) void k_gemm_cd128(
    const bf16_t* __restrict__ A, const bf16_t* __restrict__ Bt,
    int N, int Ktiles, int lda, int ldb,
    float* __restrict__ C, bf16_t* __restrict__ Cb,
    const float* __restrict__ bias) {
    __shared__ bf16_t lds[32768];   // 64 KB
    const int tid = threadIdx.x;
    const int wid = tid >> 6, lane = tid & 63;
    const int bx = (blockIdx.x & 7) * ((int)gridDim.x >> 3) + (blockIdx.x >> 3);  // XCD swizzle
    const int ntile = N >> 7;
    const int m0 = (bx / ntile) << 7;
    const int n0 = (bx % ntile) << 7;
    const int wr = wid >> 2, wc = wid & 3;
    f32x4 acc[4][2] = {};

    const int srow = tid >> 3;
    const int k8p = (tid & 7) ^ (srow & 7);
    const bf16_t* apA = A + (size_t)(m0 + srow) * lda + k8p * 8;
    const bf16_t* apB = Bt + (size_t)(n0 + srow) * ldb + k8p * 8;

    auto stageA = [&](int slot, int kt) {
        char* b0 = (char*)lds + slot * 16384 + wid * 1024;
        const bf16_t* src = apA + kt * 64;
        gload16(src, b0);
        gload16(src + (size_t)64 * lda, b0 + 8192);
    };
    auto stageB = [&](int slot, int kt) {
        char* b0 = (char*)lds + 32768 + slot * 16384 + wid * 1024;
        const bf16_t* src = apB + kt * 64;
        gload16(src, b0);
        gload16(src + (size_t)64 * ldb, b0 + 8192);
    };

    const int lm = lane & 15, lq = lane >> 4;

    const bf16_t* pA0[4]; const bf16_t* pA1[4];
    const bf16_t* pB0[2]; const bf16_t* pB1[2];
    #pragma unroll
    for (int i = 0; i < 4; ++i) {
        const int rr = lm + i * 16;
        const int e0 = wr * 4096 + rr * 64 + (lq ^ (rr & 7)) * 8;
        pA0[i] = lds + e0;
        pA1[i] = lds + (e0 ^ 32);
    }
    #pragma unroll
    for (int j = 0; j < 2; ++j) {
        const int rr = wc * 32 + lm + j * 16;
        const int e0 = 16384 + rr * 64 + (lq ^ (rr & 7)) * 8;
        pB0[j] = lds + e0;
        pB1[j] = lds + (e0 ^ 32);
    }

    auto body = [&](int t, int s) {
        asm volatile("s_waitcnt vmcnt(0)" ::: "memory");
        __builtin_amdgcn_sched_barrier(0);
        __builtin_amdgcn_s_barrier();
        __builtin_amdgcn_sched_barrier(0);
        if (t + 1 < Ktiles) {
            stageA(s ^ 1, t + 1);
            stageB(s ^ 1, t + 1);
        }
        {   // ks = 0
            bf16x8 fa[4], fb[2];
            #pragma unroll
            for (int i = 0; i < 4; ++i) fa[i] = *(const bf16x8*)(pA0[i] + s * 8192);
            #pragma unroll
            for (int j = 0; j < 2; ++j) fb[j] = *(const bf16x8*)(pB0[j] + s * 8192);
            __builtin_amdgcn_s_setprio(1);
            #pragma unroll
            for (int i = 0; i < 4; ++i)
                #pragma unroll
                for (int j = 0; j < 2; ++j)
                    acc[i][j] = __builtin_amdgcn_mfma_f32_16x16x32_bf16(fa[i], fb[j], acc[i][j], 0, 0, 0);
            __builtin_amdgcn_s_setprio(0);
        }
        {   // ks = 1
            bf16x8 fa[4], fb[2];
            #pragma unroll
            for (int i = 0; i < 4; ++i) fa[i] = *(const bf16x8*)(pA1[i] + s * 8192);
            #pragma unroll
            for (int j = 0; j < 2; ++j) fb[j] = *(const bf16x8*)(pB1[j] + s * 8192);
            __builtin_amdgcn_s_setprio(1);
            #pragma unroll
            for (int i = 0; i < 4; ++i)
                #pragma unroll
                for (int j = 0; j < 2; ++j)
                    acc[i][j] = __builtin_amdgcn_mfma_f32_16x16x32_bf16(fa[i], fb[j], acc[i][j], 0, 0, 0);
            __builtin_amdgcn_s_setprio(0);
        }
    };

    stageA(0, 0);
    stageB(0, 0);
    for (int tt = 0; tt < (Ktiles >> 1); ++tt) {
        body(2 * tt, 0);
        body(2 * tt + 1, 1);
    }

    // C/D layout (m89): col = lane&15, row = (lane>>4)*4 + reg
    const int row0 = m0 + wr * 64 + lq * 4;
    const int col0 = n0 + wc * 32 + lm;
    #pragma unroll
    for (int i = 0; i < 4; ++i) {
        #pragma unroll
        for (int j = 0; j < 2; ++j) {
            #pragma unroll
            for (int r = 0; r < 4; ++r) {
                const int row = row0 + i * 16 + r;
                const int c = col0 + j * 16;
                float v = acc[i][j][r];
                if (EPI == EPI_BF16) Cb[(size_t)row * N + c] = (bf16_t)v;
                else                 C[(size_t)row * N + c] = v + bias[c];
            }
        }
    }
}

// ---------------- 2-phase 128x128 GEMM (short-K: partk, dt) ----------------
template <int EPI>
__global__ __launch_bounds__(512) void k_gemm_bt(
    const bf16_t* __restrict__ A, const bf16_t* __restrict__ Bt,
    int M, int N, int Kloop, int lda, int ldb,
    float* __restrict__ C, bf16_t* __restrict__ Cb,
    const float* __restrict__ bias,
    float* __restrict__ o_part) {
    __shared__ bf16_t sA[2][128 * 32];
    __shared__ bf16_t sB[2][128 * 32];
    const int tid = threadIdx.x;
    const int wid = tid >> 6, lane = tid & 63;
    const int bx = (blockIdx.x & 7) * ((int)gridDim.x >> 3) + (blockIdx.x >> 3);  // XCD swizzle
    int m0, n0, k0 = 0, seg = 0;
    if (EPI == EPI_PARTK) {
        m0 = (bx & 31) << 7;
        n0 = 0;
        seg = bx >> 5;
        k0 = seg * KSEG;
    } else {
        const int ntile = N >> 7;
        m0 = (bx / ntile) << 7;
        n0 = (bx % ntile) << 7;
    }
    const int wr = wid >> 2, wc = wid & 3;   // 2x4 wave grid; wave tile 64x32
    f32x4 acc[4][2] = {};

    const bf16_t* ap = A + (size_t)(m0 + (tid >> 2)) * lda + (tid & 3) * 8 + k0;
    const bf16_t* bp = Bt + (size_t)(n0 + (tid >> 2)) * ldb + (tid & 3) * 8 + k0;
    const int lm = lane & 15, lk = (lane >> 4) * 8;

    auto stage = [&](int buf, int kt) {
        char* dA = (char*)sA[buf] + wid * 1024;
        char* dB = (char*)sB[buf] + wid * 1024;
        gload16(ap + kt, dA);
        gload16(bp + kt, dB);
    };

    stage(0, 0);
    __syncthreads();
    int cur = 0;
    for (int kt = 0; kt < Kloop; kt += 32) {
        if (kt + 32 < Kloop) stage(cur ^ 1, kt + 32);
        const bf16_t* rA = sA[cur] + (wr * 64 + lm) * 32 + lk;
        const bf16_t* rB = sB[cur] + (wc * 32 + lm) * 32 + lk;
        bf16x8 fa[4], fb[2];
        #pragma unroll
        for (int i = 0; i < 4; ++i) fa[i] = *(const bf16x8*)(rA + i * 16 * 32);
        #pragma unroll
        for (int j = 0; j < 2; ++j) fb[j] = *(const bf16x8*)(rB + j * 16 * 32);
        __builtin_amdgcn_s_setprio(1);
        #pragma unroll
        for (int i = 0; i < 4; ++i)
            #pragma unroll
            for (int j = 0; j < 2; ++j)
                acc[i][j] = __builtin_amdgcn_mfma_f32_16x16x32_bf16(fa[i], fb[j], acc[i][j], 0, 0, 0);
        __builtin_amdgcn_s_setprio(0);
        __syncthreads();
        cur ^= 1;
    }

    // C/D layout (m89-verified): col = lane&15, row = (lane>>4)*4 + reg
    const int row0 = m0 + wr * 64 + (lane >> 4) * 4;
    const int col0 = n0 + wc * 32 + lm;
    float* Cp = (EPI == EPI_PARTK)
        ? o_part + (size_t)seg * ((size_t)4096 * 128)
        : C;
    #pragma unroll
    for (int i = 0; i < 4; ++i) {
        #pragma unroll
        for (int j = 0; j < 2; ++j) {
            #pragma unroll
            for (int r = 0; r < 4; ++r) {
                int row = row0 + i * 16 + r;
                int c = col0 + j * 16;
                float v = acc[i][j][r];
                if (EPI == EPI_SOFTPLUS_RB) {
                    float xv = v + bias[row];
                    float sp = fmaxf(xv, 0.f) + log1pf(__expf(-fabsf(xv)));
                    Cb[(size_t)row * N + c] = (bf16_t)sp;
                } else {  // EPI_PARTK
                    Cp[(size_t)row * 128 + c] = v;
                }
            }
        }
    }
}

// ---------------- split-K reduce + x_dbl split: dtr bf16 / B f32 / C f32 ----
__global__ __launch_bounds__(256) void k_split_reduce(
    const float* __restrict__ part, bf16_t* __restrict__ dtr,
    float* __restrict__ Bmf, float* __restrict__ Cmf) {
    int idx = blockIdx.x * 256 + threadIdx.x;   // over 4096*128
    int row = idx >> 7, c = idx & 127;
    float s = 0.f;
    #pragma unroll
    for (int g = 0; g < 8; ++g) s += part[(size_t)g * (4096 * 128) + idx];
    if (c < 64) dtr[(size_t)row * 64 + c] = (bf16_t)s;
    else if (c < 80) Bmf[(size_t)row * 16 + (c - 64)] = s;
    else if (c < 96) Cmf[(size_t)row * 16 + (c - 80)] = s;
}

// ---------------- causal depthwise conv (k=4) + bias + SiLU ----------------
__global__ __launch_bounds__(256) void k_conv(
    const bf16_t* __restrict__ xin, const float* __restrict__ cw,
    const float* __restrict__ cb, bf16_t* __restrict__ xs_b,
    bf16_t* __restrict__ xsT) {
    __shared__ float tile[64][65];
    const int tid = threadIdx.x;
    const int d0  = (blockIdx.x & 31) * 64;
    const int bl0 = (blockIdx.x >> 5) * 64;
    const int dl = tid & 63;
    const int d  = d0 + dl;
    const float w0 = cw[d * 4], w1 = cw[d * 4 + 1], w2 = cw[d * 4 + 2], w3 = cw[d * 4 + 3];
    const float bias = cb[d];
    const int l0 = bl0 & (LL - 1);   // tiles never cross a batch boundary
    #pragma unroll 4
    for (int i = 0; i < 16; ++i) {
        const int blr = (tid >> 6) + i * 4;
        const int bl = bl0 + blr;
        const int l  = l0 + blr;
        const bf16_t* rp = xin + (size_t)bl * DINNER + d;
        float acc = fmaf(w3, (float)rp[0], bias);
        if (l >= 1) acc = fmaf(w2, (float)rp[-(int)DINNER], acc);
        if (l >= 2) acc = fmaf(w1, (float)rp[-2 * (int)DINNER], acc);
        if (l >= 3) acc = fmaf(w0, (float)rp[-3 * (int)DINNER], acc);
        float sv = acc / (1.f + __expf(-acc));
        xs_b[(size_t)bl * DINNER + d] = (bf16_t)sv;
        tile[dl][blr] = sv;
    }
    __syncthreads();
    const int dr = tid >> 2;
    const int q  = tid & 3;
    bf16_t* op = xsT + (size_t)(d0 + dr) * (BB * LL) + bl0 + q * 16;
    bf16x8 v0, v1;
    #pragma unroll
    for (int j = 0; j < 8; ++j) v0[j] = (bf16_t)tile[dr][q * 16 + j];
    #pragma unroll
    for (int j = 0; j < 8; ++j) v1[j] = (bf16_t)tile[dr][q * 16 + 8 + j];
    reinterpret_cast<bf16x8*>(op)[0] = v0;
    reinterpret_cast<bf16x8*>(op)[1] = v1;
}

// ================= chunked selective scan, lane-owns-channel =================
// alpha/beta/H stored as bf16 (multiplicative states; dt/xs/z already bf16).

__global__ __launch_bounds__(256) void k_scan_p1(
    const bf16_t* __restrict__ dtT, const bf16_t* __restrict__ xsT,
    const float* __restrict__ Bm, const float* __restrict__ A_log,
    bf16_t* __restrict__ alpha, bf16_t* __restrict__ beta) {
    __shared__ float sB[CHUNK * 16];   // 2 KB
    const int db = blockIdx.x & 7;
    const int ck = (blockIdx.x >> 3) & (NC - 1);
    const int b  = blockIdx.x >> 9;
    const int tid = threadIdx.x;
    const int d  = db * 256 + tid;
    const int t0 = ck * CHUNK;

    const float* Bsrc = Bm + ((size_t)b * LL + t0) * 16;
    sB[tid] = Bsrc[tid];
    sB[tid + 256] = Bsrc[tid + 256];

    f32x4 a2[4];
    #pragma unroll
    for (int q = 0; q < 4; ++q) {
        f32x4 av = reinterpret_cast<const f32x4*>(A_log + d * 16)[q];
        #pragma unroll
        for (int j = 0; j < 4; ++j) a2[q][j] = -__expf(av[j]) * 1.44269504f;
    }
    const bf16x8* dtp = reinterpret_cast<const bf16x8*>(dtT + (size_t)d * (BB * LL) + b * LL + t0);
    const bf16x8* xsp = reinterpret_cast<const bf16x8*>(xsT + (size_t)d * (BB * LL) + b * LL + t0);

    bf16x8 dtl[4], xsl[4];
    #pragma unroll
    for (int q = 0; q < 4; ++q) dtl[q] = dtp[q];
    #pragma unroll
    for (int q = 0; q < 4; ++q) xsl[q] = xsp[q];

    __syncthreads();

    // alpha = exp2(a2[s] * sum_t dtv) — product of per-step exps collapses to
    // one exp2 per state (saves 512 v_mul/thread); beta keeps the recurrence.
    float be[16];
    #pragma unroll
    for (int s = 0; s < 16; ++s) be[s] = 0.f;
    float dtsum = 0.f;

    #pragma unroll
    for (int t = 0; t < CHUNK; ++t) {
        float dtv = (float)dtl[t >> 3][t & 7];
        float xv  = (float)xsl[t >> 3][t & 7];
        float dtx = dtv * xv;
        dtsum += dtv;
        #pragma unroll
        for (int q = 0; q < 4; ++q) {
            f32x4 Bq = *reinterpret_cast<const f32x4*>(sB + t * 16 + q * 4);
            #pragma unroll
            for (int j = 0; j < 4; ++j) {
                const int s = q * 4 + j;
                float dA = EXP2F(dtv * a2[q][j]);
                be[s] = fmaf(be[s], dA, dtx * Bq[j]);
            }
        }
    }
    bf16_t* ap = alpha + ((size_t)(b * NC + ck)) * (DINNER * 16) + (size_t)d * 16;
    bf16_t* bp = beta  + ((size_t)(b * NC + ck)) * (DINNER * 16) + (size_t)d * 16;
    bf16x8 av0, av1, bv0, bv1;
    #pragma unroll
    for (int j = 0; j < 8; ++j) {
        av0[j] = (bf16_t)EXP2F(a2[j >> 2][j & 3] * dtsum);
        av1[j] = (bf16_t)EXP2F(a2[(j + 8) >> 2][j & 3] * dtsum);
        bv0[j] = (bf16_t)be[j];
        bv1[j] = (bf16_t)be[8 + j];
    }
    reinterpret_cast<bf16x8*>(ap)[0] = av0;
    reinterpret_cast<bf16x8*>(ap)[1] = av1;
    reinterpret_cast<bf16x8*>(bp)[0] = bv0;
    reinterpret_cast<bf16x8*>(bp)[1] = bv1;
}

__global__ __launch_bounds__(256) void k_scan_p2(
    const bf16_t* __restrict__ alpha, const bf16_t* __restrict__ beta,
    bf16_t* __restrict__ H) {
    const int gid = blockIdx.x * 256 + threadIdx.x;   // over B*DINNER*16
    const int b = gid >> 15, r = gid & 32767;
    float h = 0.f;
    #pragma unroll 8
    for (int ck = 0; ck < NC; ++ck) {
        const size_t i = ((size_t)(b * NC + ck)) * 32768 + r;
        H[i] = (bf16_t)h;
        h = fmaf((float)alpha[i], h, (float)beta[i]);
    }
}

__global__ __launch_bounds__(256) void k_scan_p3(
    const bf16_t* __restrict__ dtT, const bf16_t* __restrict__ xsT,
    const float* __restrict__ Bm, const float* __restrict__ Cm,
    const bf16_t* __restrict__ zsT, const float* __restrict__ A_log,
    const float* __restrict__ Dp, const bf16_t* __restrict__ H,
    bf16_t* __restrict__ y) {
    __shared__ float sB[CHUNK * 16];   // 2 KB
    __shared__ float sC[CHUNK * 16];   // 2 KB
    const int db = blockIdx.x & 7;
    const int ck = (blockIdx.x >> 3) & (NC - 1);
    const int b  = blockIdx.x >> 9;
    const int tid = threadIdx.x;
    const int d  = db * 256 + tid;
    const int t0 = ck * CHUNK;

    const float* Bsrc = Bm + ((size_t)b * LL + t0) * 16;
    const float* Csrc = Cm + ((size_t)b * LL + t0) * 16;
    sB[tid] = Bsrc[tid];
    sB[tid + 256] = Bsrc[tid + 256];
    sC[tid] = Csrc[tid];
    sC[tid + 256] = Csrc[tid + 256];

    f32x4 a2[4];
    #pragma unroll
    for (int q = 0; q < 4; ++q) {
        f32x4 av = reinterpret_cast<const f32x4*>(A_log + d * 16)[q];
        #pragma unroll
        for (int j = 0; j < 4; ++j) a2[q][j] = -__expf(av[j]) * 1.44269504f;
    }
    const float Dd = Dp[d];
    const bf16x8* dtp = reinterpret_cast<const bf16x8*>(dtT + (size_t)d * (BB * LL) + b * LL + t0);
    const bf16x8* xsp = reinterpret_cast<const bf16x8*>(xsT + (size_t)d * (BB * LL) + b * LL + t0);
    const bf16x8* zp  = reinterpret_cast<const bf16x8*>(zsT + (size_t)d * (BB * LL) + b * LL + t0);
    bf16_t* yp = y + ((size_t)b * LL + t0) * DINNER + d;

    bf16x8 dtl[4], xsl[4], zsl[4];
    #pragma unroll
    for (int q = 0; q < 4; ++q) dtl[q] = dtp[q];
    #pragma unroll
    for (int q = 0; q < 4; ++q) xsl[q] = xsp[q];
    #pragma unroll
    for (int q = 0; q < 4; ++q) zsl[q] = zp[q];

    float h[16];
    {
        const bf16x8* hp = reinterpret_cast<const bf16x8*>(H + ((size_t)(b * NC + ck)) * 32768 + (size_t)d * 16);
        bf16x8 h0 = hp[0], h1 = hp[1];
        #pragma unroll
        for (int j = 0; j < 8; ++j) { h[j] = (float)h0[j]; h[8 + j] = (float)h1[j]; }
    }

    __syncthreads();

    #pragma unroll
    for (int t = 0; t < CHUNK; ++t) {
        float dtv = (float)dtl[t >> 3][t & 7];
        float xv  = (float)xsl[t >> 3][t & 7];
        float zv  = (float)zsl[t >> 3][t & 7];
        float dtx = dtv * xv;
        float yacc = 0.f;
        #pragma unroll
        for (int q = 0; q < 4; ++q) {
            f32x4 Bq = *reinterpret_cast<const f32x4*>(sB + t * 16 + q * 4);
            f32x4 Cq = *reinterpret_cast<const f32x4*>(sC + t * 16 + q * 4);
            #pragma unroll
            for (int j = 0; j < 4; ++j) {
                const int s = q * 4 + j;
                float dA = EXP2F(dtv * a2[q][j]);
                h[s] = fmaf(h[s], dA, dtx * Bq[j]);
                yacc = fmaf(h[s], Cq[j], yacc);
            }
        }
        float yv = (yacc + xv * Dd) * zv;   // z already silu'd
        yp[(size_t)t * DINNER] = (bf16_t)yv;
    }
}

extern "C" void kernel_launch(void* const* d_in, const int* in_sizes, int n_in,
                              void* d_out, int out_size, void* d_ws, size_t ws_size,
                              hipStream_t stream) {
    const float* x      = (const float*)d_in[0];
    const float* W_in   = (const float*)d_in[1];
    const float* conv_w = (const float*)d_in[2];
    const float* conv_b = (const float*)d_in[3];
    const float* W_xp   = (const float*)d_in[4];
    const float* W_dt   = (const float*)d_in[5];
    const float* b_dt   = (const float*)d_in[6];
    const float* A_log  = (const float*)d_in[7];
    const float* Dvec   = (const float*)d_in[8];
    const float* W_os   = (const float*)d_in[9];
    const float* W_o    = (const float*)d_in[10];
    const float* b_o    = (const float*)d_in[11];
    float* out = (float*)d_out;

    char* base = (char*)d_ws;
    size_t off = 0;
    auto alloc = [&](size_t bytes) -> char* {
        char* p = base + off;
        off += (bytes + 255) & ~(size_t)255;
        return p;
    };
    const int MR = BB * LL;  // 4096 rows
    bf16_t* x_b   = (bf16_t*)alloc((size_t)MR * DMODEL * 2);     // 8 MiB
    bf16_t* Win_b = (bf16_t*)alloc((size_t)4096 * 1024 * 2);     // 8 MiB
    bf16_t* xin_b = (bf16_t*)alloc((size_t)MR * DINNER * 2);     // 16 MiB (aliased by alpha)
    bf16_t* xs_b  = (bf16_t*)alloc((size_t)MR * DINNER * 2);     // 16 MiB
    bf16_t* zsT   = (bf16_t*)alloc((size_t)DINNER * MR * 2);     // 16 MiB
    bf16_t* xsT   = (bf16_t*)alloc((size_t)DINNER * MR * 2);     // 16 MiB
    bf16_t* dtT_b = (bf16_t*)alloc((size_t)DINNER * MR * 2);     // 16 MiB
    float*  Hbuf  = (float*)alloc((size_t)BB * NC * DINNER * 16 * 4);  // 16 MiB (aliased by partk; H uses 8 MiB as bf16)
    bf16_t* y_b   = (bf16_t*)alloc((size_t)MR * DINNER * 2);     // 16 MiB
    bf16_t* dtr_b = (bf16_t*)alloc((size_t)MR * 64 * 2);
    float*  Bmf   = (float*)alloc((size_t)MR * 16 * 4);
    float*  Cmf   = (float*)alloc((size_t)MR * 16 * 4);
    bf16_t* Wxp_b = (bf16_t*)alloc((size_t)128 * DINNER * 2);
    bf16_t* Wdt_b = (bf16_t*)alloc((size_t)DINNER * 64 * 2);
    bf16_t* WosT_b= (bf16_t*)alloc((size_t)DINNER * DMODEL * 2); // 4 MiB
    bf16_t* Wo_b  = (bf16_t*)alloc((size_t)DMODEL * DMODEL * 2); // 2 MiB
    bf16_t* Wc_b  = (bf16_t*)alloc((size_t)DMODEL * DINNER * 2); // 4 MiB

    // aliases (lifetimes disjoint):
    //   alpha (8 MiB bf16) -> xin_b (dead after k_conv)
    //   beta  (8 MiB bf16) -> x_b (dead after k_gemm256)
    //   partk (16 MiB f32) -> Hbuf; H (8 MiB bf16) -> Hbuf (partials dead after reduce)
    bf16_t* alphab = (bf16_t*)xin_b;
    bf16_t* betab  = (bf16_t*)x_b;
    float*  partk  = Hbuf;
    bf16_t* Hb     = (bf16_t*)Hbuf;

    // all bf16 conversions (x, Win, Wdt, Wo, Wxp-pad, Wos-transpose) in one launch
    k_cvt_all<<<CVT_NBT, 256, 0, stream>>>(
        x, W_in, W_dt, W_o, W_xp, W_os,
        x_b, Win_b, Wdt_b, Wo_b, Wxp_b, WosT_b);

    // Wc = Wo @ Wos^T  [1024,2048] K=1024 -> bf16 (fused output projection)
    k_gemm_cd128<EPI_BF16><<<(DMODEL / 128) * (DINNER / 128), 512, 0, stream>>>(
        Wo_b, WosT_b, DINNER, 16, DMODEL, DMODEL, nullptr, Wc_b, nullptr);
    // xin = x @ Win_x^T [4096,2048] | zT = silu(Win_z @ x^T) [2048,4096] [d][t]
    k_gemm256<<<256, 512, 0, stream>>>(x_b, Win_b, xin_b, zsT);
    // conv + silu -> xs_b [t][d] bf16, xsT [d][t] bf16
    k_conv<<<(MR / 64) * (DINNER / 64), 256, 0, stream>>>(xin_b, conv_w, conv_b, xs_b, xsT);
    // x_dbl = xs @ W_xp^T, split-K x8 -> fp32 partials (aliased to Hbuf)
    k_gemm_bt<EPI_PARTK><<<8 * 32, 512, 0, stream>>>(
        xs_b, Wxp_b, MR, 128, KSEG, DINNER, DINNER,
        nullptr, nullptr, nullptr, partk);
    k_split_reduce<<<(MR * 128) / 256, 256, 0, stream>>>(partk, dtr_b, Bmf, Cmf);
    // dtT = softplus(Wdt @ dtr^T + b_dt[row])  [2048,4096] K=64 -> bf16 [d][t]
    k_gemm_bt<EPI_SOFTPLUS_RB><<<(DINNER / 128) * (MR / 128), 512, 0, stream>>>(
        Wdt_b, dtr_b, DINNER, MR, 64, 64, 64,
        nullptr, dtT_b, b_dt, nullptr);
    // chunked selective scan + gate -> y (bf16)
    k_scan_p1<<<BB * NC * (DINNER / 256), 256, 0, stream>>>(dtT_b, xsT, Bmf, A_log, alphab, betab);
    k_scan_p2<<<(BB * DINNER * DSTATE) / 256, 256, 0, stream>>>(alphab, betab, Hb);
    k_scan_p3<<<BB * NC * (DINNER / 256), 256, 0, stream>>>(dtT_b, xsT, Bmf, Cmf, zsT, A_log, Dvec, Hb, y_b);
    // out = y @ Wc^T + b_out  [4096,1024] K=2048 -> fp32
    k_gemm_cd128<EPI_BIAS><<<(MR / 128) * (DMODEL / 128), 512, 0, stream>>>(
        y_b, Wc_b, DMODEL, 32, DINNER, DINNER, out, nullptr, b_o);
}

// Round 26
// 208.578 us; speedup vs baseline: 1.4537x; 1.0158x over previous
//
#include <hip/hip_runtime.h>
#include <hip/hip_bf16.h>
#include <cmath>
#include <cstdint>

typedef __bf16 bf16_t;
typedef bf16_t bf16x8 __attribute__((ext_vector_type(8)));
typedef bf16_t bf16x4 __attribute__((ext_vector_type(4)));
typedef float f32x4 __attribute__((ext_vector_type(4)));

#define BB 2
#define LL 2048
#define DMODEL 1024
#define DINNER 2048
#define DSTATE 16
#define NC 64      // chunks over L
#define CHUNK 32   // L / NC
#define KSEG 256   // split-K segment for the x_dbl GEMM

// fast 2^x via v_exp_f32
#define EXP2F(x) __builtin_amdgcn_exp2f(x)

// ------- fused fp32 -> bf16 convert: x, Win, Wdt, Wo, W_xp(pad), Wos(T) -------
#define CVT_N0 1048576   // x      4096*1024/4
#define CVT_N1 2097152   // + Win  4096*1024/4
#define CVT_N2 2129920   // + Wdt  2048*64/4
#define CVT_N3 2392064   // + Wo   1024*1024/4
#define CVT_NB0 9344     // CVT_N3/256
#define CVT_NB1 10368    // + 1024 wxp blocks
#define CVT_NBT 10880    // + 512 wosT blocks
__global__ __launch_bounds__(256) void k_cvt_all(
    const float* __restrict__ x, const float* __restrict__ Win,
    const float* __restrict__ Wdt, const float* __restrict__ Wo,
    const float* __restrict__ Wxp, const float* __restrict__ Wos,
    bf16_t* __restrict__ x_b, bf16_t* __restrict__ Win_b,
    bf16_t* __restrict__ Wdt_b, bf16_t* __restrict__ Wo_b,
    bf16_t* __restrict__ Wxp_b, bf16_t* __restrict__ WosT_b) {
    const int tid = threadIdx.x;
    if (blockIdx.x < CVT_NB0) {
        int i = blockIdx.x * 256 + tid;
        const float* src; bf16_t* dst; int j;
        if (i < CVT_N0)      { src = x;   dst = x_b;   j = i; }
        else if (i < CVT_N1) { src = Win; dst = Win_b; j = i - CVT_N0; }
        else if (i < CVT_N2) { src = Wdt; dst = Wdt_b; j = i - CVT_N1; }
        else                 { src = Wo;  dst = Wo_b;  j = i - CVT_N2; }
        float4 v = reinterpret_cast<const float4*>(src)[j];
        bf16x4 o;
        o[0] = (bf16_t)v.x; o[1] = (bf16_t)v.y; o[2] = (bf16_t)v.z; o[3] = (bf16_t)v.w;
        reinterpret_cast<bf16x4*>(dst)[j] = o;
    } else if (blockIdx.x < CVT_NB1) {
        int i = (blockIdx.x - CVT_NB0) * 256 + tid;
        int r = i >> 11, c = i & (DINNER - 1);
        float v = (r < 96) ? Wxp[r * DINNER + c] : 0.f;
        Wxp_b[i] = (bf16_t)v;
    } else {
        __shared__ float tile[64][65];
        const int bid = blockIdx.x - CVT_NB1;
        const int m0 = (bid & 15) * 64;
        const int d0 = (bid >> 4) * 64;
        const int dl = tid & 63;
        #pragma unroll 4
        for (int i = 0; i < 16; ++i) {
            const int mr = (tid >> 6) + i * 4;
            tile[dl][mr] = Wos[(size_t)(m0 + mr) * DINNER + d0 + dl];
        }
        __syncthreads();
        const int dr = tid >> 2;
        const int q  = tid & 3;
        bf16_t* op = WosT_b + (size_t)(d0 + dr) * DMODEL + m0 + q * 16;
        bf16x8 v0, v1;
        #pragma unroll
        for (int j = 0; j < 8; ++j) v0[j] = (bf16_t)tile[dr][q * 16 + j];
        #pragma unroll
        for (int j = 0; j < 8; ++j) v1[j] = (bf16_t)tile[dr][q * 16 + 8 + j];
        reinterpret_cast<bf16x8*>(op)[0] = v0;
        reinterpret_cast<bf16x8*>(op)[1] = v1;
    }
}

// ---------------- async global->LDS helper ----------------
__device__ __forceinline__ void gload16(const void* g, void* l) {
    __builtin_amdgcn_global_load_lds(
        (const __attribute__((address_space(1))) void*)g,
        (__attribute__((address_space(3))) void*)l,
        16, 0, 0);
}

// ============ 256x256 BK=64 counted-drain GEMM: xin + zT (256 blocks) ============
// r17/r18-verified structure (0 bank conflicts, correct output, hoisted pointers).
__global__ __launch_bounds__(512) void k_gemm256(
    const bf16_t* __restrict__ x_b, const bf16_t* __restrict__ Win_b,
    bf16_t* __restrict__ xin_b, bf16_t* __restrict__ zsT) {
    __shared__ bf16_t lds[65536];   // 128 KB
    const int tid = threadIdx.x;
    const int wid = tid >> 6, lane = tid & 63;

    const int bid = (blockIdx.x & 7) * 32 + (blockIdx.x >> 3);   // XCD swizzle
    const bf16_t* A; const bf16_t* Bt; int m0, n0, sub;
    if (bid < 128) {  // xin = x @ Win_x^T  [4096, 2048]
        sub = 0; A = x_b; Bt = Win_b;
        m0 = (bid >> 3) * 256; n0 = (bid & 7) * 256;
    } else {          // zT = Win_z @ x^T   [2048, 4096] -> silu
        sub = 1; A = Win_b + (size_t)DINNER * DMODEL; Bt = x_b;
        const int t2 = bid - 128;
        m0 = (t2 >> 4) * 256; n0 = (t2 & 15) * 256;
    }
    const int wr = wid >> 2, wc = wid & 3;   // 2x4 wave grid
    f32x4 acc[8][4] = {};

    const int srow = tid >> 3;
    const int k8p = (tid & 7) ^ (srow & 7);
    const bf16_t* apA = A + (size_t)(m0 + srow) * 1024 + k8p * 8;
    const bf16_t* apB = Bt + (size_t)(n0 + srow) * 1024 + k8p * 8;

    auto stageA = [&](int slot, int kt) {
        char* b0 = (char*)lds + slot * 32768 + wid * 1024;
        const bf16_t* src = apA + kt * 64;
        gload16(src, b0);
        gload16(src + (size_t)64 * 1024, b0 + 8192);
        gload16(src + (size_t)128 * 1024, b0 + 16384);
        gload16(src + (size_t)192 * 1024, b0 + 24576);
    };
    auto stageB = [&](int slot, int kt) {
        char* b0 = (char*)lds + 65536 + slot * 32768 + wid * 1024;
        const bf16_t* src = apB + kt * 64;
        gload16(src, b0);
        gload16(src + (size_t)64 * 1024, b0 + 8192);
        gload16(src + (size_t)128 * 1024, b0 + 16384);
        gload16(src + (size_t)192 * 1024, b0 + 24576);
    };

    const int lm = lane & 15, lq = lane >> 4;

    const bf16_t* pA0[8]; const bf16_t* pA1[8];
    const bf16_t* pB0[4]; const bf16_t* pB1[4];
    #pragma unroll
    for (int i = 0; i < 8; ++i) {
        const int rr = lm + i * 16;
        const int e0 = wr * 8192 + rr * 64 + (lq ^ (rr & 7)) * 8;
        pA0[i] = lds + e0;
        pA1[i] = lds + (e0 ^ 32);
    }
    #pragma unroll
    for (int j = 0; j < 4; ++j) {
        const int rr = (wc & 1) * 64 + lm + j * 16;
        const int e0 = 32768 + (wc >> 1) * 8192 + rr * 64 + (lq ^ (rr & 7)) * 8;
        pB0[j] = lds + e0;
        pB1[j] = lds + (e0 ^ 32);
    }

    auto body = [&](int t, int s) {   // s is a literal at every call site
        asm volatile("s_waitcnt vmcnt(0)" ::: "memory");
        __builtin_amdgcn_sched_barrier(0);
        __builtin_amdgcn_s_barrier();
        __builtin_amdgcn_sched_barrier(0);
        if (t + 1 < 16) {
            stageA(s ^ 1, t + 1);
            stageB(s ^ 1, t + 1);
        }
        {   // ks = 0
            bf16x8 fa[8], fb[4];
            #pragma unroll
            for (int i = 0; i < 8; ++i) fa[i] = *(const bf16x8*)(pA0[i] + s * 16384);
            #pragma unroll
            for (int j = 0; j < 4; ++j) fb[j] = *(const bf16x8*)(pB0[j] + s * 16384);
            __builtin_amdgcn_s_setprio(1);
            #pragma unroll
            for (int i = 0; i < 8; ++i)
                #pragma unroll
                for (int j = 0; j < 4; ++j)
                    acc[i][j] = __builtin_amdgcn_mfma_f32_16x16x32_bf16(fa[i], fb[j], acc[i][j], 0, 0, 0);
            __builtin_amdgcn_s_setprio(0);
        }
        {   // ks = 1
            bf16x8 fa[8], fb[4];
            #pragma unroll
            for (int i = 0; i < 8; ++i) fa[i] = *(const bf16x8*)(pA1[i] + s * 16384);
            #pragma unroll
            for (int j = 0; j < 4; ++j) fb[j] = *(const bf16x8*)(pB1[j] + s * 16384);
            __builtin_amdgcn_s_setprio(1);
            #pragma unroll
            for (int i = 0; i < 8; ++i)
                #pragma unroll
                for (int j = 0; j < 4; ++j)
                    acc[i][j] = __builtin_amdgcn_mfma_f32_16x16x32_bf16(fa[i], fb[j], acc[i][j], 0, 0, 0);
            __builtin_amdgcn_s_setprio(0);
        }
    };

    stageA(0, 0);
    stageB(0, 0);
    for (int tt = 0; tt < 8; ++tt) {
        body(2 * tt, 0);
        body(2 * tt + 1, 1);
    }

    // C/D layout (m89): col = lane&15, row = (lane>>4)*4 + reg
    const int row0 = m0 + wr * 128 + lq * 4;
    const int col0 = n0 + wc * 64 + lm;
    #pragma unroll
    for (int i = 0; i < 8; ++i) {
        #pragma unroll
        for (int j = 0; j < 4; ++j) {
            #pragma unroll
            for (int r = 0; r < 4; ++r) {
                const int row = row0 + i * 16 + r;
                const int c = col0 + j * 16;
                float v = acc[i][j][r];
                if (sub == 0) xin_b[(size_t)row * DINNER + c] = (bf16_t)v;
                else          zsT[(size_t)row * (BB * LL) + c] = (bf16_t)(v / (1.f + __expf(-v)));
            }
        }
    }
}

enum { EPI_BF16 = 0, EPI_BIAS = 1, EPI_SOFTPLUS_RB = 3, EPI_PARTK = 4 };

// ======== 128x128 BK=64 counted-drain GEMM (long-K tail: Wc, out) ========
template <int EPI>
__global__ __launch_bounds__(512) void k_gemm_cd128(
    const bf16_t* __restrict__ A, const bf16_t* __restrict__ Bt,
    int N, int Ktiles, int lda, int ldb,
    float* __restrict__ C, bf16_t* __restrict__ Cb,
    const float* __restrict__ bias) {
    __shared__ bf16_t lds[32768];   // 64 KB
    const int tid = threadIdx.x;
    const int wid = tid >> 6, lane = tid & 63;
    const int bx = (blockIdx.x & 7) * ((int)gridDim.x >> 3) + (blockIdx.x >> 3);  // XCD swizzle
    const int ntile = N >> 7;
    const int m0 = (bx / ntile) << 7;
    const int n0 = (bx % ntile) << 7;
    const int wr = wid >> 2, wc = wid & 3;
    f32x4 acc[4][2] = {};

    const int srow = tid >> 3;
    const int k8p = (tid & 7) ^ (srow & 7);
    const bf16_t* apA = A + (size_t)(m0 + srow) * lda + k8p * 8;
    const bf16_t* apB = Bt + (size_t)(n0 + srow) * ldb + k8p * 8;

    auto stageA = [&](int slot, int kt) {
        char* b0 = (char*)lds + slot * 16384 + wid * 1024;
        const bf16_t* src = apA + kt * 64;
        gload16(src, b0);
        gload16(src + (size_t)64 * lda, b0 + 8192);
    };
    auto stageB = [&](int slot, int kt) {
        char* b0 = (char*)lds + 32768 + slot * 16384 + wid * 1024;
        const bf16_t* src = apB + kt * 64;
        gload16(src, b0);
        gload16(src + (size_t)64 * ldb, b0 + 8192);
    };

    const int lm = lane & 15, lq = lane >> 4;

    const bf16_t* pA0[4]; const bf16_t* pA1[4];
    const bf16_t* pB0[2]; const bf16_t* pB1[2];
    #pragma unroll
    for (int i = 0; i < 4; ++i) {
        const int rr = lm + i * 16;
        const int e0 = wr * 4096 + rr * 64 + (lq ^ (rr & 7)) * 8;
        pA0[i] = lds + e0;
        pA1[i] = lds + (e0 ^ 32);
    }
    #pragma unroll
    for (int j = 0; j < 2; ++j) {
        const int rr = wc * 32 + lm + j * 16;
        const int e0 = 16384 + rr * 64 + (lq ^ (rr & 7)) * 8;
        pB0[j] = lds + e0;
        pB1[j] = lds + (e0 ^ 32);
    }

    auto body = [&](int t, int s) {
        asm volatile("s_waitcnt vmcnt(0)" ::: "memory");
        __builtin_amdgcn_sched_barrier(0);
        __builtin_amdgcn_s_barrier();
        __builtin_amdgcn_sched_barrier(0);
        if (t + 1 < Ktiles) {
            stageA(s ^ 1, t + 1);
            stageB(s ^ 1, t + 1);
        }
        {   // ks = 0
            bf16x8 fa[4], fb[2];
            #pragma unroll
            for (int i = 0; i < 4; ++i) fa[i] = *(const bf16x8*)(pA0[i] + s * 8192);
            #pragma unroll
            for (int j = 0; j < 2; ++j) fb[j] = *(const bf16x8*)(pB0[j] + s * 8192);
            __builtin_amdgcn_s_setprio(1);
            #pragma unroll
            for (int i = 0; i < 4; ++i)
                #pragma unroll
                for (int j = 0; j < 2; ++j)
                    acc[i][j] = __builtin_amdgcn_mfma_f32_16x16x32_bf16(fa[i], fb[j], acc[i][j], 0, 0, 0);
            __builtin_amdgcn_s_setprio(0);
        }
        {   // ks = 1
            bf16x8 fa[4], fb[2];
            #pragma unroll
            for (int i = 0; i < 4; ++i) fa[i] = *(const bf16x8*)(pA1[i] + s * 8192);
            #pragma unroll
            for (int j = 0; j < 2; ++j) fb[j] = *(const bf16x8*)(pB1[j] + s * 8192);
            __builtin_amdgcn_s_setprio(1);
            #pragma unroll
            for (int i = 0; i < 4; ++i)
                #pragma unroll
                for (int j = 0; j < 2; ++j)
                    acc[i][j] = __builtin_amdgcn_mfma_f32_16x16x32_bf16(fa[i], fb[j], acc[i][j], 0, 0, 0);
            __builtin_amdgcn_s_setprio(0);
        }
    };

    stageA(0, 0);
    stageB(0, 0);
    for (int tt = 0; tt < (Ktiles >> 1); ++tt) {
        body(2 * tt, 0);
        body(2 * tt + 1, 1);
    }

    // C/D layout (m89): col = lane&15, row = (lane>>4)*4 + reg
    const int row0 = m0 + wr * 64 + lq * 4;
    const int col0 = n0 + wc * 32 + lm;
    #pragma unroll
    for (int i = 0; i < 4; ++i) {
        #pragma unroll
        for (int j = 0; j < 2; ++j) {
            #pragma unroll
            for (int r = 0; r < 4; ++r) {
                const int row = row0 + i * 16 + r;
                const int c = col0 + j * 16;
                float v = acc[i][j][r];
                if (EPI == EPI_BF16) Cb[(size_t)row * N + c] = (bf16_t)v;
                else                 C[(size_t)row * N + c] = v + bias[c];
            }
        }
    }
}

// ---------------- 2-phase 128x128 GEMM (short-K: partk, dt) ----------------
// EPI_PARTK writes bf16 partials (r25: halves split-K traffic; fp32 acc kept
// in-register, 8-way final sum stays fp32 in k_split_reduce).
template <int EPI>
__global__ __launch_bounds__(512) void k_gemm_bt(
    const bf16_t* __restrict__ A, const bf16_t* __restrict__ Bt,
    int M, int N, int Kloop, int lda, int ldb,
    float* __restrict__ C, bf16_t* __restrict__ Cb,
    const float* __restrict__ bias,
    bf16_t* __restrict__ o_part) {
    __shared__ bf16_t sA[2][128 * 32];
    __shared__ bf16_t sB[2][128 * 32];
    const int tid = threadIdx.x;
    const int wid = tid >> 6, lane = tid & 63;
    const int bx = (blockIdx.x & 7) * ((int)gridDim.x >> 3) + (blockIdx.x >> 3);  // XCD swizzle
    int m0, n0, k0 = 0, seg = 0;
    if (EPI == EPI_PARTK) {
        m0 = (bx & 31) << 7;
        n0 = 0;
        seg = bx >> 5;
        k0 = seg * KSEG;
    } else {
        const int ntile = N >> 7;
        m0 = (bx / ntile) << 7;
        n0 = (bx % ntile) << 7;
    }
    const int wr = wid >> 2, wc = wid & 3;   // 2x4 wave grid; wave tile 64x32
    f32x4 acc[4][2] = {};

    const bf16_t* ap = A + (size_t)(m0 + (tid >> 2)) * lda + (tid & 3) * 8 + k0;
    const bf16_t* bp = Bt + (size_t)(n0 + (tid >> 2)) * ldb + (tid & 3) * 8 + k0;
    const int lm = lane & 15, lk = (lane >> 4) * 8;

    auto stage = [&](int buf, int kt) {
        char* dA = (char*)sA[buf] + wid * 1024;
        char* dB = (char*)sB[buf] + wid * 1024;
        gload16(ap + kt, dA);
        gload16(bp + kt, dB);
    };

    stage(0, 0);
    __syncthreads();
    int cur = 0;
    for (int kt = 0; kt < Kloop; kt += 32) {
        if (kt + 32 < Kloop) stage(cur ^ 1, kt + 32);
        const bf16_t* rA = sA[cur] + (wr * 64 + lm) * 32 + lk;
        const bf16_t* rB = sB[cur] + (wc * 32 + lm) * 32 + lk;
        bf16x8 fa[4], fb[2];
        #pragma unroll
        for (int i = 0; i < 4; ++i) fa[i] = *(const bf16x8*)(rA + i * 16 * 32);
        #pragma unroll
        for (int j = 0; j < 2; ++j) fb[j] = *(const bf16x8*)(rB + j * 16 * 32);
        __builtin_amdgcn_s_setprio(1);
        #pragma unroll
        for (int i = 0; i < 4; ++i)
            #pragma unroll
            for (int j = 0; j < 2; ++j)
                acc[i][j] = __builtin_amdgcn_mfma_f32_16x16x32_bf16(fa[i], fb[j], acc[i][j], 0, 0, 0);
        __builtin_amdgcn_s_setprio(0);
        __syncthreads();
        cur ^= 1;
    }

    // C/D layout (m89-verified): col = lane&15, row = (lane>>4)*4 + reg
    const int row0 = m0 + wr * 64 + (lane >> 4) * 4;
    const int col0 = n0 + wc * 32 + lm;
    bf16_t* Cpb = (EPI == EPI_PARTK)
        ? o_part + (size_t)seg * ((size_t)4096 * 128)
        : nullptr;
    #pragma unroll
    for (int i = 0; i < 4; ++i) {
        #pragma unroll
        for (int j = 0; j < 2; ++j) {
            #pragma unroll
            for (int r = 0; r < 4; ++r) {
                int row = row0 + i * 16 + r;
                int c = col0 + j * 16;
                float v = acc[i][j][r];
                if (EPI == EPI_SOFTPLUS_RB) {
                    float xv = v + bias[row];
                    float sp = fmaxf(xv, 0.f) + log1pf(__expf(-fabsf(xv)));
                    Cb[(size_t)row * N + c] = (bf16_t)sp;
                } else {  // EPI_PARTK
                    Cpb[(size_t)row * 128 + c] = (bf16_t)v;
                }
            }
        }
    }
}

// ---------------- split-K reduce + x_dbl split: dtr bf16 / B f32 / C f32 ----
__global__ __launch_bounds__(256) void k_split_reduce(
    const bf16_t* __restrict__ part, bf16_t* __restrict__ dtr,
    float* __restrict__ Bmf, float* __restrict__ Cmf) {
    int idx = blockIdx.x * 256 + threadIdx.x;   // over 4096*128
    int row = idx >> 7, c = idx & 127;
    float s = 0.f;
    #pragma unroll
    for (int g = 0; g < 8; ++g) s += (float)part[(size_t)g * (4096 * 128) + idx];
    if (c < 64) dtr[(size_t)row * 64 + c] = (bf16_t)s;
    else if (c < 80) Bmf[(size_t)row * 16 + (c - 64)] = s;
    else if (c < 96) Cmf[(size_t)row * 16 + (c - 80)] = s;
}

// ---------------- causal depthwise conv (k=4) + bias + SiLU ----------------
__global__ __launch_bounds__(256) void k_conv(
    const bf16_t* __restrict__ xin, const float* __restrict__ cw,
    const float* __restrict__ cb, bf16_t* __restrict__ xs_b,
    bf16_t* __restrict__ xsT) {
    __shared__ float tile[64][65];
    const int tid = threadIdx.x;
    const int d0  = (blockIdx.x & 31) * 64;
    const int bl0 = (blockIdx.x >> 5) * 64;
    const int dl = tid & 63;
    const int d  = d0 + dl;
    const float w0 = cw[d * 4], w1 = cw[d * 4 + 1], w2 = cw[d * 4 + 2], w3 = cw[d * 4 + 3];
    const float bias = cb[d];
    const int l0 = bl0 & (LL - 1);   // tiles never cross a batch boundary
    #pragma unroll 4
    for (int i = 0; i < 16; ++i) {
        const int blr = (tid >> 6) + i * 4;
        const int bl = bl0 + blr;
        const int l  = l0 + blr;
        const bf16_t* rp = xin + (size_t)bl * DINNER + d;
        float acc = fmaf(w3, (float)rp[0], bias);
        if (l >= 1) acc = fmaf(w2, (float)rp[-(int)DINNER], acc);
        if (l >= 2) acc = fmaf(w1, (float)rp[-2 * (int)DINNER], acc);
        if (l >= 3) acc = fmaf(w0, (float)rp[-3 * (int)DINNER], acc);
        float sv = acc / (1.f + __expf(-acc));
        xs_b[(size_t)bl * DINNER + d] = (bf16_t)sv;
        tile[dl][blr] = sv;
    }
    __syncthreads();
    const int dr = tid >> 2;
    const int q  = tid & 3;
    bf16_t* op = xsT + (size_t)(d0 + dr) * (BB * LL) + bl0 + q * 16;
    bf16x8 v0, v1;
    #pragma unroll
    for (int j = 0; j < 8; ++j) v0[j] = (bf16_t)tile[dr][q * 16 + j];
    #pragma unroll
    for (int j = 0; j < 8; ++j) v1[j] = (bf16_t)tile[dr][q * 16 + 8 + j];
    reinterpret_cast<bf16x8*>(op)[0] = v0;
    reinterpret_cast<bf16x8*>(op)[1] = v1;
}

// ================= chunked selective scan, lane-owns-channel =================
// alpha/beta/H stored as bf16 (multiplicative states; dt/xs/z already bf16).

__global__ __launch_bounds__(256) void k_scan_p1(
    const bf16_t* __restrict__ dtT, const bf16_t* __restrict__ xsT,
    const float* __restrict__ Bm, const float* __restrict__ A_log,
    bf16_t* __restrict__ alpha, bf16_t* __restrict__ beta) {
    __shared__ float sB[CHUNK * 16];   // 2 KB
    const int db = blockIdx.x & 7;
    const int ck = (blockIdx.x >> 3) & (NC - 1);
    const int b  = blockIdx.x >> 9;
    const int tid = threadIdx.x;
    const int d  = db * 256 + tid;
    const int t0 = ck * CHUNK;

    const float* Bsrc = Bm + ((size_t)b * LL + t0) * 16;
    sB[tid] = Bsrc[tid];
    sB[tid + 256] = Bsrc[tid + 256];

    f32x4 a2[4];
    #pragma unroll
    for (int q = 0; q < 4; ++q) {
        f32x4 av = reinterpret_cast<const f32x4*>(A_log + d * 16)[q];
        #pragma unroll
        for (int j = 0; j < 4; ++j) a2[q][j] = -__expf(av[j]) * 1.44269504f;
    }
    const bf16x8* dtp = reinterpret_cast<const bf16x8*>(dtT + (size_t)d * (BB * LL) + b * LL + t0);
    const bf16x8* xsp = reinterpret_cast<const bf16x8*>(xsT + (size_t)d * (BB * LL) + b * LL + t0);

    bf16x8 dtl[4], xsl[4];
    #pragma unroll
    for (int q = 0; q < 4; ++q) dtl[q] = dtp[q];
    #pragma unroll
    for (int q = 0; q < 4; ++q) xsl[q] = xsp[q];

    __syncthreads();

    // alpha = exp2(a2[s] * sum_t dtv) — product of per-step exps collapses to
    // one exp2 per state (saves 512 v_mul/thread); beta keeps the recurrence.
    float be[16];
    #pragma unroll
    for (int s = 0; s < 16; ++s) be[s] = 0.f;
    float dtsum = 0.f;

    #pragma unroll
    for (int t = 0; t < CHUNK; ++t) {
        float dtv = (float)dtl[t >> 3][t & 7];
        float xv  = (float)xsl[t >> 3][t & 7];
        float dtx = dtv * xv;
        dtsum += dtv;
        #pragma unroll
        for (int q = 0; q < 4; ++q) {
            f32x4 Bq = *reinterpret_cast<const f32x4*>(sB + t * 16 + q * 4);
            #pragma unroll
            for (int j = 0; j < 4; ++j) {
                const int s = q * 4 + j;
                float dA = EXP2F(dtv * a2[q][j]);
                be[s] = fmaf(be[s], dA, dtx * Bq[j]);
            }
        }
    }
    bf16_t* ap = alpha + ((size_t)(b * NC + ck)) * (DINNER * 16) + (size_t)d * 16;
    bf16_t* bp = beta  + ((size_t)(b * NC + ck)) * (DINNER * 16) + (size_t)d * 16;
    bf16x8 av0, av1, bv0, bv1;
    #pragma unroll
    for (int j = 0; j < 8; ++j) {
        av0[j] = (bf16_t)EXP2F(a2[j >> 2][j & 3] * dtsum);
        av1[j] = (bf16_t)EXP2F(a2[(j + 8) >> 2][j & 3] * dtsum);
        bv0[j] = (bf16_t)be[j];
        bv1[j] = (bf16_t)be[8 + j];
    }
    reinterpret_cast<bf16x8*>(ap)[0] = av0;
    reinterpret_cast<bf16x8*>(ap)[1] = av1;
    reinterpret_cast<bf16x8*>(bp)[0] = bv0;
    reinterpret_cast<bf16x8*>(bp)[1] = bv1;
}

__global__ __launch_bounds__(256) void k_scan_p2(
    const bf16_t* __restrict__ alpha, const bf16_t* __restrict__ beta,
    bf16_t* __restrict__ H) {
    const int gid = blockIdx.x * 256 + threadIdx.x;   // over B*DINNER*16
    const int b = gid >> 15, r = gid & 32767;
    float h = 0.f;
    #pragma unroll 8
    for (int ck = 0; ck < NC; ++ck) {
        const size_t i = ((size_t)(b * NC + ck)) * 32768 + r;
        H[i] = (bf16_t)h;
        h = fmaf((float)alpha[i], h, (float)beta[i]);
    }
}

__global__ __launch_bounds__(256) void k_scan_p3(
    const bf16_t* __restrict__ dtT, const bf16_t* __restrict__ xsT,
    const float* __restrict__ Bm, const float* __restrict__ Cm,
    const bf16_t* __restrict__ zsT, const float* __restrict__ A_log,
    const float* __restrict__ Dp, const bf16_t* __restrict__ H,
    bf16_t* __restrict__ y) {
    __shared__ float sB[CHUNK * 16];   // 2 KB
    __shared__ float sC[CHUNK * 16];   // 2 KB
    const int db = blockIdx.x & 7;
    const int ck = (blockIdx.x >> 3) & (NC - 1);
    const int b  = blockIdx.x >> 9;
    const int tid = threadIdx.x;
    const int d  = db * 256 + tid;
    const int t0 = ck * CHUNK;

    const float* Bsrc = Bm + ((size_t)b * LL + t0) * 16;
    const float* Csrc = Cm + ((size_t)b * LL + t0) * 16;
    sB[tid] = Bsrc[tid];
    sB[tid + 256] = Bsrc[tid + 256];
    sC[tid] = Csrc[tid];
    sC[tid + 256] = Csrc[tid + 256];

    f32x4 a2[4];
    #pragma unroll
    for (int q = 0; q < 4; ++q) {
        f32x4 av = reinterpret_cast<const f32x4*>(A_log + d * 16)[q];
        #pragma unroll
        for (int j = 0; j < 4; ++j) a2[q][j] = -__expf(av[j]) * 1.44269504f;
    }
    const float Dd = Dp[d];
    const bf16x8* dtp = reinterpret_cast<const bf16x8*>(dtT + (size_t)d * (BB * LL) + b * LL + t0);
    const bf16x8* xsp = reinterpret_cast<const bf16x8*>(xsT + (size_t)d * (BB * LL) + b * LL + t0);
    const bf16x8* zp  = reinterpret_cast<const bf16x8*>(zsT + (size_t)d * (BB * LL) + b * LL + t0);
    bf16_t* yp = y + ((size_t)b * LL + t0) * DINNER + d;

    bf16x8 dtl[4], xsl[4], zsl[4];
    #pragma unroll
    for (int q = 0; q < 4; ++q) dtl[q] = dtp[q];
    #pragma unroll
    for (int q = 0; q < 4; ++q) xsl[q] = xsp[q];
    #pragma unroll
    for (int q = 0; q < 4; ++q) zsl[q] = zp[q];

    float h[16];
    {
        const bf16x8* hp = reinterpret_cast<const bf16x8*>(H + ((size_t)(b * NC + ck)) * 32768 + (size_t)d * 16);
        bf16x8 h0 = hp[0], h1 = hp[1];
        #pragma unroll
        for (int j = 0; j < 8; ++j) { h[j] = (float)h0[j]; h[8 + j] = (float)h1[j]; }
    }

    __syncthreads();

    #pragma unroll
    for (int t = 0; t < CHUNK; ++t) {
        float dtv = (float)dtl[t >> 3][t & 7];
        float xv  = (float)xsl[t >> 3][t & 7];
        float zv  = (float)zsl[t >> 3][t & 7];
        float dtx = dtv * xv;
        float yacc = 0.f;
        #pragma unroll
        for (int q = 0; q < 4; ++q) {
            f32x4 Bq = *reinterpret_cast<const f32x4*>(sB + t * 16 + q * 4);
            f32x4 Cq = *reinterpret_cast<const f32x4*>(sC + t * 16 + q * 4);
            #pragma unroll
            for (int j = 0; j < 4; ++j) {
                const int s = q * 4 + j;
                float dA = EXP2F(dtv * a2[q][j]);
                h[s] = fmaf(h[s], dA, dtx * Bq[j]);
                yacc = fmaf(h[s], Cq[j], yacc);
            }
        }
        float yv = (yacc + xv * Dd) * zv;   // z already silu'd
        yp[(size_t)t * DINNER] = (bf16_t)yv;
    }
}

extern "C" void kernel_launch(void* const* d_in, const int* in_sizes, int n_in,
                              void* d_out, int out_size, void* d_ws, size_t ws_size,
                              hipStream_t stream) {
    const float* x      = (const float*)d_in[0];
    const float* W_in   = (const float*)d_in[1];
    const float* conv_w = (const float*)d_in[2];
    const float* conv_b = (const float*)d_in[3];
    const float* W_xp   = (const float*)d_in[4];
    const float* W_dt   = (const float*)d_in[5];
    const float* b_dt   = (const float*)d_in[6];
    const float* A_log  = (const float*)d_in[7];
    const float* Dvec   = (const float*)d_in[8];
    const float* W_os   = (const float*)d_in[9];
    const float* W_o    = (const float*)d_in[10];
    const float* b_o    = (const float*)d_in[11];
    float* out = (float*)d_out;

    char* base = (char*)d_ws;
    size_t off = 0;
    auto alloc = [&](size_t bytes) -> char* {
        char* p = base + off;
        off += (bytes + 255) & ~(size_t)255;
        return p;
    };
    const int MR = BB * LL;  // 4096 rows
    bf16_t* x_b   = (bf16_t*)alloc((size_t)MR * DMODEL * 2);     // 8 MiB
    bf16_t* Win_b = (bf16_t*)alloc((size_t)4096 * 1024 * 2);     // 8 MiB
    bf16_t* xin_b = (bf16_t*)alloc((size_t)MR * DINNER * 2);     // 16 MiB (aliased by alpha)
    bf16_t* xs_b  = (bf16_t*)alloc((size_t)MR * DINNER * 2);     // 16 MiB
    bf16_t* zsT   = (bf16_t*)alloc((size_t)DINNER * MR * 2);     // 16 MiB
    bf16_t* xsT   = (bf16_t*)alloc((size_t)DINNER * MR * 2);     // 16 MiB
    bf16_t* dtT_b = (bf16_t*)alloc((size_t)DINNER * MR * 2);     // 16 MiB
    float*  Hbuf  = (float*)alloc((size_t)BB * NC * DINNER * 16 * 4);  // 16 MiB (aliased by partk bf16 8 MiB; H bf16 8 MiB)
    bf16_t* y_b   = (bf16_t*)alloc((size_t)MR * DINNER * 2);     // 16 MiB
    bf16_t* dtr_b = (bf16_t*)alloc((size_t)MR * 64 * 2);
    float*  Bmf   = (float*)alloc((size_t)MR * 16 * 4);
    float*  Cmf   = (float*)alloc((size_t)MR * 16 * 4);
    bf16_t* Wxp_b = (bf16_t*)alloc((size_t)128 * DINNER * 2);
    bf16_t* Wdt_b = (bf16_t*)alloc((size_t)DINNER * 64 * 2);
    bf16_t* WosT_b= (bf16_t*)alloc((size_t)DINNER * DMODEL * 2); // 4 MiB
    bf16_t* Wo_b  = (bf16_t*)alloc((size_t)DMODEL * DMODEL * 2); // 2 MiB
    bf16_t* Wc_b  = (bf16_t*)alloc((size_t)DMODEL * DINNER * 2); // 4 MiB

    // aliases (lifetimes disjoint):
    //   alpha (8 MiB bf16) -> xin_b (dead after k_conv)
    //   beta  (8 MiB bf16) -> x_b (dead after k_gemm256)
    //   partk (8 MiB bf16) -> Hbuf; H (8 MiB bf16) -> Hbuf (partials dead after reduce)
    bf16_t* alphab = (bf16_t*)xin_b;
    bf16_t* betab  = (bf16_t*)x_b;
    bf16_t* partk  = (bf16_t*)Hbuf;
    bf16_t* Hb     = (bf16_t*)Hbuf;

    // all bf16 conversions (x, Win, Wdt, Wo, Wxp-pad, Wos-transpose) in one launch
    k_cvt_all<<<CVT_NBT, 256, 0, stream>>>(
        x, W_in, W_dt, W_o, W_xp, W_os,
        x_b, Win_b, Wdt_b, Wo_b, Wxp_b, WosT_b);

    // Wc = Wo @ Wos^T  [1024,2048] K=1024 -> bf16 (fused output projection)
    k_gemm_cd128<EPI_BF16><<<(DMODEL / 128) * (DINNER / 128), 512, 0, stream>>>(
        Wo_b, WosT_b, DINNER, 16, DMODEL, DMODEL, nullptr, Wc_b, nullptr);
    // xin = x @ Win_x^T [4096,2048] | zT = silu(Win_z @ x^T) [2048,4096] [d][t]
    k_gemm256<<<256, 512, 0, stream>>>(x_b, Win_b, xin_b, zsT);
    // conv + silu -> xs_b [t][d] bf16, xsT [d][t] bf16
    k_conv<<<(MR / 64) * (DINNER / 64), 256, 0, stream>>>(xin_b, conv_w, conv_b, xs_b, xsT);
    // x_dbl = xs @ W_xp^T, split-K x8 -> bf16 partials (aliased to Hbuf)
    k_gemm_bt<EPI_PARTK><<<8 * 32, 512, 0, stream>>>(
        xs_b, Wxp_b, MR, 128, KSEG, DINNER, DINNER,
        nullptr, nullptr, nullptr, partk);
    k_split_reduce<<<(MR * 128) / 256, 256, 0, stream>>>(partk, dtr_b, Bmf, Cmf);
    // dtT = softplus(Wdt @ dtr^T + b_dt[row])  [2048,4096] K=64 -> bf16 [d][t]
    k_gemm_bt<EPI_SOFTPLUS_RB><<<(DINNER / 128) * (MR / 128), 512, 0, stream>>>(
        Wdt_b, dtr_b, DINNER, MR, 64, 64, 64,
        nullptr, dtT_b, b_dt, nullptr);
    // chunked selective scan + gate -> y (bf16)
    k_scan_p1<<<BB * NC * (DINNER / 256), 256, 0, stream>>>(dtT_b, xsT, Bmf, A_log, alphab, betab);
    k_scan_p2<<<(BB * DINNER * DSTATE) / 256, 256, 0, stream>>>(alphab, betab, Hb);
    k_scan_p3<<<BB * NC * (DINNER / 256), 256, 0, stream>>>(dtT_b, xsT, Bmf, Cmf, zsT, A_log, Dvec, Hb, y_b);
    // out = y @ Wc^T + b_out  [4096,1024] K=2048 -> fp32
    k_gemm_cd128<EPI_BIAS><<<(MR / 128) * (DMODEL / 128), 512, 0, stream>>>(
        y_b, Wc_b, DMODEL, 32, DINNER, DINNER, out, nullptr, b_o);
}